// Round 6
// baseline (296.169 us; speedup 1.0000x reference)
//
#include <hip/hip_runtime.h>
#include <hip/hip_bf16.h>
#include <cstdint>
#include <cstddef>

typedef float f32x4 __attribute__((ext_vector_type(4)));
typedef float f32x16 __attribute__((ext_vector_type(16)));
typedef __bf16 bf16x8 __attribute__((ext_vector_type(8)));
typedef unsigned short us8v __attribute__((ext_vector_type(8)));
typedef unsigned short us4v __attribute__((ext_vector_type(4)));

constexpr int B_ = 2, S_ = 2048, D_ = 2048, NH = 16, NKV = 4, HD = 128;
constexpr int QKV_O = (NH + 2 * NKV) * HD;  // 3072

__device__ __forceinline__ unsigned short f2b(float f) {
  union { float f; uint32_t u; } v{f};
  uint32_t r = v.u + 0x7fffu + ((v.u >> 16) & 1u);  // RNE
  return (unsigned short)(r >> 16);
}

__device__ __forceinline__ uint32_t pk2(float a, float b) {
  union { __bf16 h[2]; uint32_t u; } v;
  v.h[0] = (__bf16)a; v.h[1] = (__bf16)b;
  return v.u;
}

__device__ __forceinline__ bf16x8 as_bf(us8v x) {
  union { us8v u; bf16x8 b; } v; v.u = x; return v.b;
}

__device__ __forceinline__ f32x4 mfma16(bf16x8 a, bf16x8 b, f32x4 c) {
  return __builtin_amdgcn_mfma_f32_16x16x32_bf16(a, b, c, 0, 0, 0);
}
__device__ __forceinline__ f32x16 mfma32(bf16x8 a, bf16x8 b, f32x16 c) {
  return __builtin_amdgcn_mfma_f32_32x32x16_bf16(a, b, c, 0, 0, 0);
}

// async global->LDS, 16B per lane; LDS dest = wave-uniform base + lane*16
__device__ __forceinline__ void gload_lds16(const unsigned short* g, unsigned short* l) {
  __builtin_amdgcn_global_load_lds(
      (const __attribute__((address_space(1))) unsigned int*)(uintptr_t)g,
      (__attribute__((address_space(3))) unsigned int*)(uintptr_t)l, 16, 0, 0);
}

// ---------------- f32 -> bf16 conversion (vectorized) ----------------
__global__ void f2b_kernel(const float* __restrict__ in, unsigned short* __restrict__ out, int n4) {
  int i = blockIdx.x * blockDim.x + threadIdx.x;
  if (i >= n4) return;
  float4 v = reinterpret_cast<const float4*>(in)[i];
  us4v o;
  o[0] = f2b(v.x); o[1] = f2b(v.y); o[2] = f2b(v.z); o[3] = f2b(v.w);
  reinterpret_cast<us4v*>(out)[i] = o;
}

// ---------------- RoPE cos/sin table: [S][64] ----------------
__global__ void rope_table_kernel(float* __restrict__ cs, float* __restrict__ sn) {
  int idx = blockIdx.x * blockDim.x + threadIdx.x;
  if (idx >= S_ * 64) return;
  int t = idx >> 6, i = idx & 63;
  float inv = __expf(-((float)(2 * i) / 128.0f) * 9.210340371976184f);
  float fr = (float)t * inv;
  cs[idx] = cosf(fr);
  sn[idx] = sinf(fr);
}

// ---------------- RoPE apply; Q -> [b,h,s,d] (pre-scaled), K -> K2 [bk][d/8][s][8] ----------------
__global__ void rope_qk_kernel(const float* __restrict__ qkv, const float* __restrict__ cs,
                               const float* __restrict__ sn, unsigned short* __restrict__ Q,
                               unsigned short* __restrict__ K2) {
  int idx = blockIdx.x * blockDim.x + threadIdx.x;
  if (idx >= B_ * S_ * 20 * 64) return;
  int pr = idx & 63;
  int tmp = idx >> 6;
  int hh = tmp % 20; tmp /= 20;
  int s = tmp % S_;
  int b = tmp / S_;
  int off = (hh < 16) ? hh * HD : NH * HD + (hh - 16) * HD;
  float2 v = *reinterpret_cast<const float2*>(qkv + (size_t)(b * S_ + s) * QKV_O + off + 2 * pr);
  float c0 = cs[s * 64 + pr], s0 = sn[s * 64 + pr];
  float mult = (hh < 16) ? 0.08838834764831845f : 1.0f;  // fold attn scale into Q
  float o0 = (v.x * c0 - v.y * s0) * mult;
  float o1 = (v.x * s0 + v.y * c0) * mult;
  unsigned int packed = (unsigned)f2b(o0) | ((unsigned)f2b(o1) << 16);
  if (hh < 16) {
    *reinterpret_cast<unsigned*>(Q + (((size_t)(b * NH + hh) * S_ + s) * HD + 2 * pr)) = packed;
  } else {
    int bk = b * NKV + (hh - 16);
    size_t a = (((size_t)bk * 16 + (pr >> 2)) * S_ + s) * 8 + (pr & 3) * 2;
    *reinterpret_cast<unsigned*>(K2 + a) = packed;
  }
}

// ---------------- V pack: qkv f32 -> V2 bf16 [bk][s/8][d=128][8] ----------------
__global__ __launch_bounds__(128) void v8_kernel(const float* __restrict__ qkv,
                                                 unsigned short* __restrict__ V2) {
  int d = threadIdx.x;          // 0..127
  int g = blockIdx.x;           // s-group 0..255
  int bk = blockIdx.y;          // b*4+kvh
  const float* src = qkv + (size_t)((bk >> 2) * S_ + g * 8) * QKV_O + (NH + NKV) * HD +
                     (bk & 3) * HD + d;
  us8v o;
#pragma unroll
  for (int j = 0; j < 8; j++) o[j] = f2b(src[(size_t)j * QKV_O]);
  *reinterpret_cast<us8v*>(V2 + (((size_t)bk * 256 + g) * 128 + d) * 8) = o;
}

// ---------------- bf16 GEMM (m97 structure): C[M,N] = A[M,K] * B[N,K]^T ----------------
__global__ __launch_bounds__(256) void gemm_bt_kernel(const unsigned short* __restrict__ A,
                                                      const unsigned short* __restrict__ Bm,
                                                      float* __restrict__ C, int M, int N, int K) {
  __shared__ unsigned short As[128 * 32];
  __shared__ unsigned short Bs[128 * 32];
  int t = threadIdx.x;
  int lane = t & 63, wid = t >> 6;
  int wr = wid >> 1, wc = wid & 1;
  int g = lane >> 4, c = lane & 15;
  int m0 = blockIdx.y * 128, n0 = blockIdx.x * 128;

  int r0 = wid * 32 + (lane >> 2);
  int cc = (lane & 3) * 8;
  const unsigned short* pa = A + (size_t)(m0 + r0) * K + cc;
  const unsigned short* pb = Bm + (size_t)(n0 + r0) * K + cc;
  unsigned short* lA = As + wid * 1024;
  unsigned short* lB = Bs + wid * 1024;

  f32x4 acc[4][4] = {};
  for (int k0 = 0; k0 < K; k0 += 32) {
    gload_lds16(pa + k0, lA);
    gload_lds16(pa + (size_t)16 * K + k0, lA + 512);
    gload_lds16(pb + k0, lB);
    gload_lds16(pb + (size_t)16 * K + k0, lB + 512);
    __syncthreads();
    bf16x8 af[4], bfv[4];
#pragma unroll
    for (int m = 0; m < 4; m++)
      af[m] = as_bf(*reinterpret_cast<const us8v*>(&As[(wr * 64 + m * 16 + c) * 32 + g * 8]));
#pragma unroll
    for (int n = 0; n < 4; n++)
      bfv[n] = as_bf(*reinterpret_cast<const us8v*>(&Bs[(wc * 64 + n * 16 + c) * 32 + g * 8]));
#pragma unroll
    for (int m = 0; m < 4; m++)
#pragma unroll
      for (int n = 0; n < 4; n++) acc[m][n] = mfma16(af[m], bfv[n], acc[m][n]);
    __syncthreads();
  }
#pragma unroll
  for (int m = 0; m < 4; m++)
#pragma unroll
    for (int n = 0; n < 4; n++)
#pragma unroll
      for (int r = 0; r < 4; r++)
        C[(size_t)(m0 + wr * 64 + m * 16 + g * 4 + r) * N + n0 + wc * 64 + n * 16 + c] =
            acc[m][n][r];
}

// ---------------- Flash attention: balanced pair-split causal schedule ----------------
// 64 q-tiles (32 rows). Tile t needs kv tiles [0,t]; split at H_t=(t+1)/2.
// Wave does lo(own tile) then hi(partner tile 63-own); partner = wid^4 in same block.
// Every wave = 32-33 kv-steps => perfectly balanced grid (256 blocks, 1/CU).
__global__ __launch_bounds__(512, 1) void attn32_kernel(const unsigned short* __restrict__ Q,
                                                        const unsigned short* __restrict__ K2,
                                                        const unsigned short* __restrict__ V2,
                                                        unsigned short* __restrict__ O) {
  __shared__ float stO[8][4][16][64];  // 128 KB partial-O stash
  __shared__ float stM[8][64];
  __shared__ float stL[8][64];

  int t = threadIdx.x;
  int lane = t & 63, wid = t >> 6;
  int l31 = lane & 31, hi = lane >> 5;
  int bq = blockIdx.x, bh = blockIdx.y;
  int b = bh >> 4, h = bh & 15, kvh = h >> 2;
  int bk = b * NKV + kvh;
  int j = wid & 3, side = wid >> 2;
  int a = bq * 4 + j;                // 0..31
  int tA = side ? 63 - a : a;        // sweep-1 tile (stash lo-half)
  int tB = 63 - tA;                  // sweep-2 tile (compute hi-half, merge, write)

  const unsigned short* Kp = K2 + (((size_t)bk * 16 + hi) * S_ + l31) * 8;
  const unsigned short* Vp = V2 + (((size_t)bk * 256 + hi) * 128 + l31) * 8;

  bf16x8 qf[8];
  bf16x8 kA[8], kB[8];
  f32x16 oacc[4];
  float mrow, lsum;

  auto loadQ = [&](int tile) {
    const unsigned short* Qp =
        Q + ((size_t)(b * NH + h) * S_ + tile * 32) * HD + (size_t)l31 * HD + hi * 8;
#pragma unroll
    for (int kk = 0; kk < 8; kk++)
      qf[kk] = as_bf(*reinterpret_cast<const us8v*>(Qp + kk * 16));
  };

  auto loadK = [&](bf16x8(&kf)[8], int kv) {
    const unsigned short* kp = Kp + (size_t)kv * 8;
#pragma unroll
    for (int kk = 0; kk < 8; kk++)
      kf[kk] = as_bf(*reinterpret_cast<const us8v*>(kp + (size_t)kk * 2 * S_ * 8));
  };

  auto step = [&](bf16x8(&kf)[8], bf16x8(&kn)[8], int kv0, int kend, int qw) {
    bf16x8 vf[8];
    const unsigned short* vp = Vp + (size_t)kv0 * 128;
#pragma unroll
    for (int dt = 0; dt < 4; dt++) {
      vf[2 * dt] = as_bf(*reinterpret_cast<const us8v*>(vp + dt * 256));
      vf[2 * dt + 1] = as_bf(*reinterpret_cast<const us8v*>(vp + 2048 + dt * 256));
    }
    if (kv0 + 32 <= kend) loadK(kn, kv0 + 32);

    f32x16 sa = {}, sb = {};
    __builtin_amdgcn_s_setprio(1);
#pragma unroll
    for (int kk = 0; kk < 4; kk++) {
      sa = mfma32(kf[2 * kk], qf[2 * kk], sa);
      sb = mfma32(kf[2 * kk + 1], qf[2 * kk + 1], sb);
    }
    __builtin_amdgcn_s_setprio(0);
    f32x16 s = sa + sb;

    if (kv0 == qw) {  // diagonal tile: causal mask
      int qg = qw + l31;
#pragma unroll
      for (int r = 0; r < 16; r++) {
        int kvg = kv0 + (r & 3) + 8 * (r >> 2) + 4 * hi;
        if (kvg > qg) s[r] = -1e30f;
      }
    }

    float pm = fmaxf(s[0], s[1]);
#pragma unroll
    for (int r = 2; r < 16; r++) pm = fmaxf(pm, s[r]);
    pm = fmaxf(pm, __shfl_xor(pm, 32));

    bool nore = __all(pm <= mrow + 8.0f) != 0;  // defer-max (T13), wave-uniform
    float mn = nore ? mrow : fmaxf(mrow, pm);
    float part = 0.0f;
    uint32_t w[8];
#pragma unroll
    for (int jj = 0; jj < 8; jj++) {
      float e0 = __expf(s[2 * jj] - mn);
      float e1 = __expf(s[2 * jj + 1] - mn);
      part += e0 + e1;
      w[jj] = pk2(e0, e1);
    }
    part += __shfl_xor(part, 32);
    if (nore) {
      lsum += part;
    } else {
      float alpha = __expf(mrow - mn);  // per q-row l31
      lsum = lsum * alpha + part;
      mrow = mn;
      // oacc rows are crow(r,hi): shuffle per-row alpha (wave-uniform branch -> shfl safe)
#pragma unroll
      for (int r = 0; r < 16; r++) {
        float af = __shfl(alpha, (r & 3) + 8 * (r >> 2) + 4 * hi);
#pragma unroll
        for (int dt = 0; dt < 4; dt++) oacc[dt][r] *= af;
      }
    }

    uint32_t sw[8];
#pragma unroll
    for (int jj = 0; jj < 8; jj++) sw[jj] = __shfl_xor(w[jj], 32);
    union { uint32_t u[4]; bf16x8 v; } pa0, pa1;
    if (hi == 0) {
      pa0.u[0] = w[0]; pa0.u[1] = w[1]; pa0.u[2] = sw[0]; pa0.u[3] = sw[1];
      pa1.u[0] = w[4]; pa1.u[1] = w[5]; pa1.u[2] = sw[4]; pa1.u[3] = sw[5];
    } else {
      pa0.u[0] = sw[2]; pa0.u[1] = sw[3]; pa0.u[2] = w[2]; pa0.u[3] = w[3];
      pa1.u[0] = sw[6]; pa1.u[1] = sw[7]; pa1.u[2] = w[6]; pa1.u[3] = w[7];
    }

    __builtin_amdgcn_s_setprio(1);
#pragma unroll
    for (int dt = 0; dt < 4; dt++) {
      oacc[dt] = mfma32(pa0.v, vf[2 * dt], oacc[dt]);
      oacc[dt] = mfma32(pa1.v, vf[2 * dt + 1], oacc[dt]);
    }
    __builtin_amdgcn_s_setprio(0);
  };

  auto sweep = [&](int tile, int tb, int te) {  // kv tiles [tb, te] inclusive
    loadQ(tile);
    int qw = tile * 32;
    int kv0 = tb * 32, kend = te * 32;
    loadK(kA, kv0);
    while (true) {
      step(kA, kB, kv0, kend, qw);
      kv0 += 32;
      if (kv0 > kend) break;
      step(kB, kA, kv0, kend, qw);
      kv0 += 32;
      if (kv0 > kend) break;
    }
  };

  // ---- sweep 1: lo(tA) = kv tiles [0, HA) ----
#pragma unroll
  for (int dt = 0; dt < 4; dt++) oacc[dt] = {};
  mrow = -1e30f; lsum = 0.0f;
  int HA = (tA + 1) >> 1;
  if (HA > 0) sweep(tA, 0, HA - 1);

  // stash partial for partner
#pragma unroll
  for (int dt = 0; dt < 4; dt++)
#pragma unroll
    for (int r = 0; r < 16; r++) stO[wid][dt][r][lane] = oacc[dt][r];
  stM[wid][lane] = mrow;
  stL[wid][lane] = lsum;

  // ---- sweep 2: hi(tB) = kv tiles [HB, tB] ----
#pragma unroll
  for (int dt = 0; dt < 4; dt++) oacc[dt] = {};
  mrow = -1e30f; lsum = 0.0f;
  int HB = (tB + 1) >> 1;
  sweep(tB, HB, tB);

  __syncthreads();

  // ---- merge with partner's lo(tB) and write rows of tB ----
  int p = wid ^ 4;
  float m1 = stM[p][lane], l1 = stL[p][lane];
  float mm = fmaxf(mrow, m1);
  float fo = __expf(mrow - mm), fp = __expf(m1 - mm);
  float lf = lsum * fo + l1 * fp;
  float il = 1.0f / lf;
  unsigned short* Op = O + ((size_t)b * S_ + tB * 32) * D_ + h * HD;
#pragma unroll
  for (int r = 0; r < 16; r++) {
    int row = (r & 3) + 8 * (r >> 2) + 4 * hi;
    float fo_r = __shfl(fo, row);
    float fp_r = __shfl(fp, row);
    float il_r = __shfl(il, row);
#pragma unroll
    for (int dt = 0; dt < 4; dt++) {
      float v = (oacc[dt][r] * fo_r + stO[p][dt][r][lane] * fp_r) * il_r;
      Op[(size_t)row * D_ + dt * 32 + l31] = f2b(v);
    }
  }
}

extern "C" void kernel_launch(void* const* d_in, const int* in_sizes, int n_in, void* d_out,
                              int out_size, void* d_ws, size_t ws_size, hipStream_t stream) {
  const float* x = (const float*)d_in[0];
  const float* w_qkv = (const float*)d_in[1];
  const float* w_o = (const float*)d_in[2];
  float* out = (float*)d_out;

  char* ws = (char*)d_ws;
  size_t off = 0;
  auto alloc = [&](size_t bytes) -> void* {
    void* p = ws + off;
    off += (bytes + 255) & ~(size_t)255;
    return p;
  };
  const size_t nx = (size_t)B_ * S_ * D_;
  const size_t nwqkv = (size_t)QKV_O * D_;
  const size_t nwo = (size_t)D_ * D_;
  unsigned short* xb = (unsigned short*)alloc(nx * 2);
  unsigned short* wqkvb = (unsigned short*)alloc(nwqkv * 2);
  unsigned short* wob = (unsigned short*)alloc(nwo * 2);
  float* qkv = (float*)alloc((size_t)B_ * S_ * QKV_O * 4);
  unsigned short* Qb = (unsigned short*)alloc((size_t)B_ * NH * S_ * HD * 2);
  unsigned short* K2b = (unsigned short*)alloc((size_t)B_ * NKV * S_ * HD * 2);
  unsigned short* V2b = (unsigned short*)alloc((size_t)B_ * NKV * HD * S_ * 2);
  unsigned short* attnb = (unsigned short*)alloc((size_t)B_ * S_ * D_ * 2);
  float* cs = (float*)alloc((size_t)S_ * 64 * 4);
  float* sn = (float*)alloc((size_t)S_ * 64 * 4);

  f2b_kernel<<<dim3((nx / 4 + 255) / 256), 256, 0, stream>>>(x, xb, nx / 4);
  f2b_kernel<<<dim3((nwqkv / 4 + 255) / 256), 256, 0, stream>>>(w_qkv, wqkvb, nwqkv / 4);
  f2b_kernel<<<dim3((nwo / 4 + 255) / 256), 256, 0, stream>>>(w_o, wob, nwo / 4);
  rope_table_kernel<<<dim3((S_ * 64 + 255) / 256), 256, 0, stream>>>(cs, sn);

  gemm_bt_kernel<<<dim3(QKV_O / 128, (B_ * S_) / 128), 256, 0, stream>>>(xb, wqkvb, qkv,
                                                                         B_ * S_, QKV_O, D_);

  rope_qk_kernel<<<dim3((B_ * S_ * 20 * 64 + 255) / 256), 256, 0, stream>>>(qkv, cs, sn, Qb, K2b);
  v8_kernel<<<dim3(S_ / 8, B_ * NKV), 128, 0, stream>>>(qkv, V2b);

  attn32_kernel<<<dim3(8, 32), 512, 0, stream>>>(Qb, K2b, V2b, attnb);

  gemm_bt_kernel<<<dim3(D_ / 128, (B_ * S_) / 128), 256, 0, stream>>>(attnb, wob, out,
                                                                      B_ * S_, D_, D_);
}

// Round 7
// 236.135 us; speedup vs baseline: 1.2542x; 1.2542x over previous
//
#include <hip/hip_runtime.h>
#include <hip/hip_bf16.h>
#include <cstdint>
#include <cstddef>

typedef float f32x4 __attribute__((ext_vector_type(4)));
typedef float f32x16 __attribute__((ext_vector_type(16)));
typedef __bf16 bf16x8 __attribute__((ext_vector_type(8)));
typedef unsigned short us8v __attribute__((ext_vector_type(8)));
typedef unsigned short us4v __attribute__((ext_vector_type(4)));

constexpr int B_ = 2, S_ = 2048, D_ = 2048, NH = 16, NKV = 4, HD = 128;
constexpr int QKV_O = (NH + 2 * NKV) * HD;  // 3072

__device__ __forceinline__ unsigned short f2b(float f) {
  union { float f; uint32_t u; } v{f};
  uint32_t r = v.u + 0x7fffu + ((v.u >> 16) & 1u);  // RNE
  return (unsigned short)(r >> 16);
}

__device__ __forceinline__ uint32_t pk2(float a, float b) {
  union { __bf16 h[2]; uint32_t u; } v;
  v.h[0] = (__bf16)a; v.h[1] = (__bf16)b;
  return v.u;
}

__device__ __forceinline__ bf16x8 as_bf(us8v x) {
  union { us8v u; bf16x8 b; } v; v.u = x; return v.b;
}

__device__ __forceinline__ f32x4 mfma16(bf16x8 a, bf16x8 b, f32x4 c) {
  return __builtin_amdgcn_mfma_f32_16x16x32_bf16(a, b, c, 0, 0, 0);
}
__device__ __forceinline__ f32x16 mfma32(bf16x8 a, bf16x8 b, f32x16 c) {
  return __builtin_amdgcn_mfma_f32_32x32x16_bf16(a, b, c, 0, 0, 0);
}

// async global->LDS, 16B per lane; LDS dest = wave-uniform base + lane*16
__device__ __forceinline__ void gload_lds16(const unsigned short* g, unsigned short* l) {
  __builtin_amdgcn_global_load_lds(
      (const __attribute__((address_space(1))) unsigned int*)(uintptr_t)g,
      (__attribute__((address_space(3))) unsigned int*)(uintptr_t)l, 16, 0, 0);
}

// ---------------- f32 -> bf16 conversion (vectorized) ----------------
__global__ void f2b_kernel(const float* __restrict__ in, unsigned short* __restrict__ out, int n4) {
  int i = blockIdx.x * blockDim.x + threadIdx.x;
  if (i >= n4) return;
  float4 v = reinterpret_cast<const float4*>(in)[i];
  us4v o;
  o[0] = f2b(v.x); o[1] = f2b(v.y); o[2] = f2b(v.z); o[3] = f2b(v.w);
  reinterpret_cast<us4v*>(out)[i] = o;
}

// ---------------- RoPE cos/sin table: [S][64] ----------------
__global__ void rope_table_kernel(float* __restrict__ cs, float* __restrict__ sn) {
  int idx = blockIdx.x * blockDim.x + threadIdx.x;
  if (idx >= S_ * 64) return;
  int t = idx >> 6, i = idx & 63;
  float inv = __expf(-((float)(2 * i) / 128.0f) * 9.210340371976184f);
  float fr = (float)t * inv;
  cs[idx] = cosf(fr);
  sn[idx] = sinf(fr);
}

// ---------------- RoPE apply; Q -> [b,h,s,d] (pre-scaled), K -> K2 [bk][d/8][s][8] ----------------
__global__ void rope_qk_kernel(const float* __restrict__ qkv, const float* __restrict__ cs,
                               const float* __restrict__ sn, unsigned short* __restrict__ Q,
                               unsigned short* __restrict__ K2) {
  int idx = blockIdx.x * blockDim.x + threadIdx.x;
  if (idx >= B_ * S_ * 20 * 64) return;
  int pr = idx & 63;
  int tmp = idx >> 6;
  int hh = tmp % 20; tmp /= 20;
  int s = tmp % S_;
  int b = tmp / S_;
  int off = (hh < 16) ? hh * HD : NH * HD + (hh - 16) * HD;
  float2 v = *reinterpret_cast<const float2*>(qkv + (size_t)(b * S_ + s) * QKV_O + off + 2 * pr);
  float c0 = cs[s * 64 + pr], s0 = sn[s * 64 + pr];
  float mult = (hh < 16) ? 0.08838834764831845f : 1.0f;  // fold attn scale into Q
  float o0 = (v.x * c0 - v.y * s0) * mult;
  float o1 = (v.x * s0 + v.y * c0) * mult;
  unsigned int packed = (unsigned)f2b(o0) | ((unsigned)f2b(o1) << 16);
  if (hh < 16) {
    *reinterpret_cast<unsigned*>(Q + (((size_t)(b * NH + hh) * S_ + s) * HD + 2 * pr)) = packed;
  } else {
    int bk = b * NKV + (hh - 16);
    size_t a = (((size_t)bk * 16 + (pr >> 2)) * S_ + s) * 8 + (pr & 3) * 2;
    *reinterpret_cast<unsigned*>(K2 + a) = packed;
  }
}

// ---------------- V pack: qkv f32 -> V2 bf16 [bk][s/8][d=128][8] ----------------
__global__ __launch_bounds__(128) void v8_kernel(const float* __restrict__ qkv,
                                                 unsigned short* __restrict__ V2) {
  int d = threadIdx.x;          // 0..127
  int g = blockIdx.x;           // s-group 0..255
  int bk = blockIdx.y;          // b*4+kvh
  const float* src = qkv + (size_t)((bk >> 2) * S_ + g * 8) * QKV_O + (NH + NKV) * HD +
                     (bk & 3) * HD + d;
  us8v o;
#pragma unroll
  for (int j = 0; j < 8; j++) o[j] = f2b(src[(size_t)j * QKV_O]);
  *reinterpret_cast<us8v*>(V2 + (((size_t)bk * 256 + g) * 128 + d) * 8) = o;
}

// ---------------- bf16 GEMM (m97 structure): C[M,N] = A[M,K] * B[N,K]^T ----------------
__global__ __launch_bounds__(256) void gemm_bt_kernel(const unsigned short* __restrict__ A,
                                                      const unsigned short* __restrict__ Bm,
                                                      float* __restrict__ C, int M, int N, int K) {
  __shared__ unsigned short As[128 * 32];
  __shared__ unsigned short Bs[128 * 32];
  int t = threadIdx.x;
  int lane = t & 63, wid = t >> 6;
  int wr = wid >> 1, wc = wid & 1;
  int g = lane >> 4, c = lane & 15;
  int m0 = blockIdx.y * 128, n0 = blockIdx.x * 128;

  int r0 = wid * 32 + (lane >> 2);
  int cc = (lane & 3) * 8;
  const unsigned short* pa = A + (size_t)(m0 + r0) * K + cc;
  const unsigned short* pb = Bm + (size_t)(n0 + r0) * K + cc;
  unsigned short* lA = As + wid * 1024;
  unsigned short* lB = Bs + wid * 1024;

  f32x4 acc[4][4] = {};
  for (int k0 = 0; k0 < K; k0 += 32) {
    gload_lds16(pa + k0, lA);
    gload_lds16(pa + (size_t)16 * K + k0, lA + 512);
    gload_lds16(pb + k0, lB);
    gload_lds16(pb + (size_t)16 * K + k0, lB + 512);
    __syncthreads();
    bf16x8 af[4], bfv[4];
#pragma unroll
    for (int m = 0; m < 4; m++)
      af[m] = as_bf(*reinterpret_cast<const us8v*>(&As[(wr * 64 + m * 16 + c) * 32 + g * 8]));
#pragma unroll
    for (int n = 0; n < 4; n++)
      bfv[n] = as_bf(*reinterpret_cast<const us8v*>(&Bs[(wc * 64 + n * 16 + c) * 32 + g * 8]));
#pragma unroll
    for (int m = 0; m < 4; m++)
#pragma unroll
      for (int n = 0; n < 4; n++) acc[m][n] = mfma16(af[m], bfv[n], acc[m][n]);
    __syncthreads();
  }
#pragma unroll
  for (int m = 0; m < 4; m++)
#pragma unroll
    for (int n = 0; n < 4; n++)
#pragma unroll
      for (int r = 0; r < 4; r++)
        C[(size_t)(m0 + wr * 64 + m * 16 + g * 4 + r) * N + n0 + wc * 64 + n * 16 + c] =
            acc[m][n][r];
}

// ---------------- Flash attention: pair-balanced causal schedule, no merge ----------------
// 64 q-tiles of 32 rows; tile t costs t+1 kv-steps. Block bq's 4 waves take tiles
// (2bq, 63-2bq, 2bq+1, 62-2bq): every block = exactly 130 steps => uniform block cost.
// Wave owns whole tile: no stash, no merge, zero LDS. Inner step = round-5 pipeline.
__global__ __launch_bounds__(256, 2) void attn32_kernel(const unsigned short* __restrict__ Q,
                                                        const unsigned short* __restrict__ K2,
                                                        const unsigned short* __restrict__ V2,
                                                        unsigned short* __restrict__ O) {
  int t = threadIdx.x;
  int lane = t & 63, wid = t >> 6;
  int l31 = lane & 31, hi = lane >> 5;
  int bh = blockIdx.y;
  int b = bh >> 4, h = bh & 15, kvh = h >> 2;
  int bk = b * NKV + kvh;

  int pidx = blockIdx.x * 2 + (wid >> 1);       // pair index 0..31
  int tw = (wid & 1) ? (63 - pidx) : pidx;      // this wave's q-tile
  int qw = tw * 32;

  const unsigned short* Qp = Q + ((size_t)(b * NH + h) * S_ + qw) * HD + (size_t)l31 * HD + hi * 8;
  const unsigned short* Kp = K2 + (((size_t)bk * 16 + hi) * S_ + l31) * 8;
  const unsigned short* Vp = V2 + (((size_t)bk * 256 + hi) * 128 + l31) * 8;

  bf16x8 qf[8];
#pragma unroll
  for (int kk = 0; kk < 8; kk++)
    qf[kk] = as_bf(*reinterpret_cast<const us8v*>(Qp + kk * 16));

  f32x16 oacc[4] = {};
  float mrow = -1e30f, lsum = 0.0f;

  bf16x8 kA[8], kB[8];

  auto loadK = [&](bf16x8(&kf)[8], int kv) {
    const unsigned short* kp = Kp + (size_t)kv * 8;
#pragma unroll
    for (int kk = 0; kk < 8; kk++)
      kf[kk] = as_bf(*reinterpret_cast<const us8v*>(kp + (size_t)kk * 2 * S_ * 8));
  };

  auto step = [&](bf16x8(&kf)[8], bf16x8(&kn)[8], int kv0) {
    bf16x8 vf[8];
    const unsigned short* vp = Vp + (size_t)kv0 * 128;
#pragma unroll
    for (int dt = 0; dt < 4; dt++) {
      vf[2 * dt] = as_bf(*reinterpret_cast<const us8v*>(vp + dt * 256));
      vf[2 * dt + 1] = as_bf(*reinterpret_cast<const us8v*>(vp + 2048 + dt * 256));
    }
    if (kv0 + 32 <= qw) loadK(kn, kv0 + 32);

    f32x16 sa = {}, sb = {};
    __builtin_amdgcn_s_setprio(1);
#pragma unroll
    for (int kk = 0; kk < 4; kk++) {
      sa = mfma32(kf[2 * kk], qf[2 * kk], sa);
      sb = mfma32(kf[2 * kk + 1], qf[2 * kk + 1], sb);
    }
    __builtin_amdgcn_s_setprio(0);
    f32x16 s = sa + sb;

    if (kv0 == qw) {  // diagonal tile: causal mask
      int qg = qw + l31;
#pragma unroll
      for (int r = 0; r < 16; r++) {
        int kvg = kv0 + (r & 3) + 8 * (r >> 2) + 4 * hi;
        if (kvg > qg) s[r] = -1e30f;
      }
    }

    float pm = fmaxf(s[0], s[1]);
#pragma unroll
    for (int r = 2; r < 16; r++) pm = fmaxf(pm, s[r]);
    pm = fmaxf(pm, __shfl_xor(pm, 32));

    bool nore = __all(pm <= mrow + 8.0f) != 0;  // defer-max (T13), wave-uniform
    float mn = nore ? mrow : fmaxf(mrow, pm);
    float part = 0.0f;
    uint32_t w[8];
#pragma unroll
    for (int jj = 0; jj < 8; jj++) {
      float e0 = __expf(s[2 * jj] - mn);
      float e1 = __expf(s[2 * jj + 1] - mn);
      part += e0 + e1;
      w[jj] = pk2(e0, e1);
    }
    part += __shfl_xor(part, 32);
    if (nore) {
      lsum += part;
    } else {
      float alpha = __expf(mrow - mn);  // per q-row l31
      lsum = lsum * alpha + part;
      mrow = mn;
      // oacc rows are crow(r,hi): shuffle per-row alpha (wave-uniform branch -> shfl safe)
#pragma unroll
      for (int r = 0; r < 16; r++) {
        float af = __shfl(alpha, (r & 3) + 8 * (r >> 2) + 4 * hi);
#pragma unroll
        for (int dt = 0; dt < 4; dt++) oacc[dt][r] *= af;
      }
    }

    uint32_t sw[8];
#pragma unroll
    for (int jj = 0; jj < 8; jj++) sw[jj] = __shfl_xor(w[jj], 32);
    union { uint32_t u[4]; bf16x8 v; } pa0, pa1;
    if (hi == 0) {
      pa0.u[0] = w[0]; pa0.u[1] = w[1]; pa0.u[2] = sw[0]; pa0.u[3] = sw[1];
      pa1.u[0] = w[4]; pa1.u[1] = w[5]; pa1.u[2] = sw[4]; pa1.u[3] = sw[5];
    } else {
      pa0.u[0] = sw[2]; pa0.u[1] = sw[3]; pa0.u[2] = w[2]; pa0.u[3] = w[3];
      pa1.u[0] = sw[6]; pa1.u[1] = sw[7]; pa1.u[2] = w[6]; pa1.u[3] = w[7];
    }

    __builtin_amdgcn_s_setprio(1);
#pragma unroll
    for (int dt = 0; dt < 4; dt++) {
      oacc[dt] = mfma32(pa0.v, vf[2 * dt], oacc[dt]);
      oacc[dt] = mfma32(pa1.v, vf[2 * dt + 1], oacc[dt]);
    }
    __builtin_amdgcn_s_setprio(0);
  };

  loadK(kA, 0);
  int kv0 = 0;
  while (true) {
    step(kA, kB, kv0);
    kv0 += 32;
    if (kv0 > qw) break;
    step(kB, kA, kv0);
    kv0 += 32;
    if (kv0 > qw) break;
  }

  // ---- epilogue: O[q=crow(r,hi)][d=dt*32+l31] ----
  float il = 1.0f / lsum;
  unsigned short* Op = O + ((size_t)b * S_ + qw) * D_ + h * HD;
#pragma unroll
  for (int r = 0; r < 16; r++) {
    int row = (r & 3) + 8 * (r >> 2) + 4 * hi;
    float sc = __shfl(il, row);
#pragma unroll
    for (int dt = 0; dt < 4; dt++)
      Op[(size_t)row * D_ + dt * 32 + l31] = f2b(oacc[dt][r] * sc);
  }
}

extern "C" void kernel_launch(void* const* d_in, const int* in_sizes, int n_in, void* d_out,
                              int out_size, void* d_ws, size_t ws_size, hipStream_t stream) {
  const float* x = (const float*)d_in[0];
  const float* w_qkv = (const float*)d_in[1];
  const float* w_o = (const float*)d_in[2];
  float* out = (float*)d_out;

  char* ws = (char*)d_ws;
  size_t off = 0;
  auto alloc = [&](size_t bytes) -> void* {
    void* p = ws + off;
    off += (bytes + 255) & ~(size_t)255;
    return p;
  };
  const size_t nx = (size_t)B_ * S_ * D_;
  const size_t nwqkv = (size_t)QKV_O * D_;
  const size_t nwo = (size_t)D_ * D_;
  unsigned short* xb = (unsigned short*)alloc(nx * 2);
  unsigned short* wqkvb = (unsigned short*)alloc(nwqkv * 2);
  unsigned short* wob = (unsigned short*)alloc(nwo * 2);
  float* qkv = (float*)alloc((size_t)B_ * S_ * QKV_O * 4);
  unsigned short* Qb = (unsigned short*)alloc((size_t)B_ * NH * S_ * HD * 2);
  unsigned short* K2b = (unsigned short*)alloc((size_t)B_ * NKV * S_ * HD * 2);
  unsigned short* V2b = (unsigned short*)alloc((size_t)B_ * NKV * HD * S_ * 2);
  unsigned short* attnb = (unsigned short*)alloc((size_t)B_ * S_ * D_ * 2);
  float* cs = (float*)alloc((size_t)S_ * 64 * 4);
  float* sn = (float*)alloc((size_t)S_ * 64 * 4);

  f2b_kernel<<<dim3((nx / 4 + 255) / 256), 256, 0, stream>>>(x, xb, nx / 4);
  f2b_kernel<<<dim3((nwqkv / 4 + 255) / 256), 256, 0, stream>>>(w_qkv, wqkvb, nwqkv / 4);
  f2b_kernel<<<dim3((nwo / 4 + 255) / 256), 256, 0, stream>>>(w_o, wob, nwo / 4);
  rope_table_kernel<<<dim3((S_ * 64 + 255) / 256), 256, 0, stream>>>(cs, sn);

  gemm_bt_kernel<<<dim3(QKV_O / 128, (B_ * S_) / 128), 256, 0, stream>>>(xb, wqkvb, qkv,
                                                                         B_ * S_, QKV_O, D_);

  rope_qk_kernel<<<dim3((B_ * S_ * 20 * 64 + 255) / 256), 256, 0, stream>>>(qkv, cs, sn, Qb, K2b);
  v8_kernel<<<dim3(S_ / 8, B_ * NKV), 128, 0, stream>>>(qkv, V2b);

  attn32_kernel<<<dim3(16, 32), 256, 0, stream>>>(Qb, K2b, V2b, attnb);

  gemm_bt_kernel<<<dim3(D_ / 128, (B_ * S_) / 128), 256, 0, stream>>>(attnb, wob, out,
                                                                      B_ * S_, D_, D_);
}

// Round 8
// 224.760 us; speedup vs baseline: 1.3177x; 1.0506x over previous
//
#include <hip/hip_runtime.h>
#include <hip/hip_bf16.h>
#include <cstdint>
#include <cstddef>

typedef float f32x4 __attribute__((ext_vector_type(4)));
typedef float f32x16 __attribute__((ext_vector_type(16)));
typedef __bf16 bf16x8 __attribute__((ext_vector_type(8)));
typedef unsigned short us8v __attribute__((ext_vector_type(8)));
typedef unsigned short us4v __attribute__((ext_vector_type(4)));

constexpr int B_ = 2, S_ = 2048, D_ = 2048, NH = 16, NKV = 4, HD = 128;
constexpr int QKV_O = (NH + 2 * NKV) * HD;  // 3072

__device__ __forceinline__ unsigned short f2b(float f) {
  union { float f; uint32_t u; } v{f};
  uint32_t r = v.u + 0x7fffu + ((v.u >> 16) & 1u);  // RNE
  return (unsigned short)(r >> 16);
}

__device__ __forceinline__ uint32_t pk2(float a, float b) {
  union { __bf16 h[2]; uint32_t u; } v;
  v.h[0] = (__bf16)a; v.h[1] = (__bf16)b;
  return v.u;
}

__device__ __forceinline__ bf16x8 as_bf(us8v x) {
  union { us8v u; bf16x8 b; } v; v.u = x; return v.b;
}

__device__ __forceinline__ f32x4 mfma16(bf16x8 a, bf16x8 b, f32x4 c) {
  return __builtin_amdgcn_mfma_f32_16x16x32_bf16(a, b, c, 0, 0, 0);
}
__device__ __forceinline__ f32x16 mfma32(bf16x8 a, bf16x8 b, f32x16 c) {
  return __builtin_amdgcn_mfma_f32_32x32x16_bf16(a, b, c, 0, 0, 0);
}

// async global->LDS, 16B per lane; LDS dest = wave-uniform base + lane*16
__device__ __forceinline__ void gload_lds16(const unsigned short* g, unsigned short* l) {
  __builtin_amdgcn_global_load_lds(
      (const __attribute__((address_space(1))) unsigned int*)(uintptr_t)g,
      (__attribute__((address_space(3))) unsigned int*)(uintptr_t)l, 16, 0, 0);
}

// ---------------- f32 -> bf16 conversion (vectorized) ----------------
__global__ void f2b_kernel(const float* __restrict__ in, unsigned short* __restrict__ out, int n4) {
  int i = blockIdx.x * blockDim.x + threadIdx.x;
  if (i >= n4) return;
  float4 v = reinterpret_cast<const float4*>(in)[i];
  us4v o;
  o[0] = f2b(v.x); o[1] = f2b(v.y); o[2] = f2b(v.z); o[3] = f2b(v.w);
  reinterpret_cast<us4v*>(out)[i] = o;
}

// ---------------- RoPE cos/sin table: [S][64] ----------------
__global__ void rope_table_kernel(float* __restrict__ cs, float* __restrict__ sn) {
  int idx = blockIdx.x * blockDim.x + threadIdx.x;
  if (idx >= S_ * 64) return;
  int t = idx >> 6, i = idx & 63;
  float inv = __expf(-((float)(2 * i) / 128.0f) * 9.210340371976184f);
  float fr = (float)t * inv;
  cs[idx] = cosf(fr);
  sn[idx] = sinf(fr);
}

// ---------------- RoPE apply; Q -> [b,h,s,d] (pre-scaled), K -> K2 [bk][d/8][s][8] ----------------
__global__ void rope_qk_kernel(const float* __restrict__ qkv, const float* __restrict__ cs,
                               const float* __restrict__ sn, unsigned short* __restrict__ Q,
                               unsigned short* __restrict__ K2) {
  int idx = blockIdx.x * blockDim.x + threadIdx.x;
  if (idx >= B_ * S_ * 20 * 64) return;
  int pr = idx & 63;
  int tmp = idx >> 6;
  int hh = tmp % 20; tmp /= 20;
  int s = tmp % S_;
  int b = tmp / S_;
  int off = (hh < 16) ? hh * HD : NH * HD + (hh - 16) * HD;
  float2 v = *reinterpret_cast<const float2*>(qkv + (size_t)(b * S_ + s) * QKV_O + off + 2 * pr);
  float c0 = cs[s * 64 + pr], s0 = sn[s * 64 + pr];
  float mult = (hh < 16) ? 0.08838834764831845f : 1.0f;  // fold attn scale into Q
  float o0 = (v.x * c0 - v.y * s0) * mult;
  float o1 = (v.x * s0 + v.y * c0) * mult;
  unsigned int packed = (unsigned)f2b(o0) | ((unsigned)f2b(o1) << 16);
  if (hh < 16) {
    *reinterpret_cast<unsigned*>(Q + (((size_t)(b * NH + hh) * S_ + s) * HD + 2 * pr)) = packed;
  } else {
    int bk = b * NKV + (hh - 16);
    size_t a = (((size_t)bk * 16 + (pr >> 2)) * S_ + s) * 8 + (pr & 3) * 2;
    *reinterpret_cast<unsigned*>(K2 + a) = packed;
  }
}

// ---------------- V pack: qkv f32 -> V2 bf16 [bk][s/8][d=128][8] ----------------
__global__ __launch_bounds__(128) void v8_kernel(const float* __restrict__ qkv,
                                                 unsigned short* __restrict__ V2) {
  int d = threadIdx.x;          // 0..127
  int g = blockIdx.x;           // s-group 0..255
  int bk = blockIdx.y;          // b*4+kvh
  const float* src = qkv + (size_t)((bk >> 2) * S_ + g * 8) * QKV_O + (NH + NKV) * HD +
                     (bk & 3) * HD + d;
  us8v o;
#pragma unroll
  for (int j = 0; j < 8; j++) o[j] = f2b(src[(size_t)j * QKV_O]);
  *reinterpret_cast<us8v*>(V2 + (((size_t)bk * 256 + g) * 128 + d) * 8) = o;
}

// ---------------- bf16 GEMM (m97 2-phase): C[M,N] = A[M,K] * B[N,K]^T ----------------
__global__ __launch_bounds__(256) void gemm_bt_kernel(const unsigned short* __restrict__ A,
                                                      const unsigned short* __restrict__ Bm,
                                                      float* __restrict__ C, int M, int N, int K) {
  __shared__ unsigned short As[128 * 32];
  __shared__ unsigned short Bs[128 * 32];
  int t = threadIdx.x;
  int lane = t & 63, wid = t >> 6;
  int wr = wid >> 1, wc = wid & 1;
  int g = lane >> 4, c = lane & 15;
  int m0 = blockIdx.y * 128, n0 = blockIdx.x * 128;

  int r0 = wid * 32 + (lane >> 2);
  int cc = (lane & 3) * 8;
  const unsigned short* pa = A + (size_t)(m0 + r0) * K + cc;
  const unsigned short* pb = Bm + (size_t)(n0 + r0) * K + cc;
  unsigned short* lA = As + wid * 1024;
  unsigned short* lB = Bs + wid * 1024;

  f32x4 acc[4][4] = {};
  for (int k0 = 0; k0 < K; k0 += 32) {
    gload_lds16(pa + k0, lA);
    gload_lds16(pa + (size_t)16 * K + k0, lA + 512);
    gload_lds16(pb + k0, lB);
    gload_lds16(pb + (size_t)16 * K + k0, lB + 512);
    __syncthreads();
    bf16x8 af[4], bfv[4];
#pragma unroll
    for (int m = 0; m < 4; m++)
      af[m] = as_bf(*reinterpret_cast<const us8v*>(&As[(wr * 64 + m * 16 + c) * 32 + g * 8]));
#pragma unroll
    for (int n = 0; n < 4; n++)
      bfv[n] = as_bf(*reinterpret_cast<const us8v*>(&Bs[(wc * 64 + n * 16 + c) * 32 + g * 8]));
#pragma unroll
    for (int m = 0; m < 4; m++)
#pragma unroll
      for (int n = 0; n < 4; n++) acc[m][n] = mfma16(af[m], bfv[n], acc[m][n]);
    __syncthreads();
  }
#pragma unroll
  for (int m = 0; m < 4; m++)
#pragma unroll
    for (int n = 0; n < 4; n++)
#pragma unroll
      for (int r = 0; r < 4; r++)
        C[(size_t)(m0 + wr * 64 + m * 16 + g * 4 + r) * N + n0 + wc * 64 + n * 16 + c] =
            acc[m][n][r];
}

// ---------------- bf16 GEMM (256x256 8-phase, T2+T3+T4+T5): C = A * B^T ----------------
// 8 waves (2M x 4N), BK=64, 128KB LDS dbuf. Swizzle: LDS slot = colslot ^ (row&7),
// applied on global SOURCE (gload_lds dest stays linear) and on ds_read address.
// Stage order per iter t (into buf^1, tile t+1): P0:B0,B1 P1:B2,B3 P2:A0,A2 P3:A1,A3.
// Counted waits: vmcnt(4) end-P1 (protects next P2/P3 A-chunks 1,3), vmcnt(2) end-P3
// (protects next P0/P1: all B + A-chunks 0,2). Never drains in main loop.
__global__ __launch_bounds__(512, 2) void gemm8p_kernel(const unsigned short* __restrict__ A,
                                                        const unsigned short* __restrict__ Bm,
                                                        float* __restrict__ C, int M, int N,
                                                        int K) {
  __shared__ unsigned short LDS[65536];  // A: [2][16384], B: +32768
  const int t = threadIdx.x;
  const int lane = t & 63, wid = t >> 6;
  const int wm = wid >> 2, wn = wid & 3;
  const int c = lane & 15, g4 = lane >> 4;
  const int m0 = blockIdx.y * 256, n0 = blockIdx.x * 256;

  // staging coords: thread -> (row-in-chunk, slot); source col-slot pre-swizzled
  const int sr = t >> 3, ss = t & 7;
  const int sg = ss ^ (sr & 7);
  const unsigned short* pa = A + (size_t)(m0 + sr) * K + sg * 8;
  const unsigned short* pb = Bm + (size_t)(n0 + sr) * K + sg * 8;
  unsigned short* ldw = (unsigned short*)&LDS[wid << 9];  // wave-uniform dest base

  f32x4 acc[8][4] = {};
  bf16x8 bf[4][2];

#define STAGE_A(buf, j, kk0) \
  gload_lds16(pa + (size_t)(64 * (j)) * K + (kk0), ldw + (buf)*16384 + (j)*4096)
#define STAGE_B(buf, j, kk0) \
  gload_lds16(pb + (size_t)(64 * (j)) * K + (kk0), ldw + 32768 + (buf)*16384 + (j)*4096)

#define LDA(buf, m, kk) \
  as_bf(*reinterpret_cast<const us8v*>( \
      &LDS[(buf)*16384 + (wm * 128 + (m)*16 + c) * 64 + ((((kk) << 2) | g4) ^ (c & 7)) * 8]))
#define LDB(buf, n, kk) \
  as_bf(*reinterpret_cast<const us8v*>( \
      &LDS[32768 + (buf)*16384 + (wn * 64 + (n)*16 + c) * 64 + ((((kk) << 2) | g4) ^ (c & 7)) * 8]))

  // prologue: stage tile 0 into buf 0, drain once
#pragma unroll
  for (int j = 0; j < 4; j++) STAGE_B(0, j, 0);
#pragma unroll
  for (int j = 0; j < 4; j++) STAGE_A(0, j, 0);
  asm volatile("s_waitcnt vmcnt(0)" ::: "memory");
  __builtin_amdgcn_s_barrier();

  const int NT = K >> 6;
  for (int tt = 0; tt < NT; ++tt) {
    const int cur = tt & 1, nxt = cur ^ 1;
    const int kn = (tt + 1) << 6;
    const bool st = (tt + 1) < NT;
    bf16x8 a00, a01, a10, a11;

#define MFMA_PAIR(mlo)                                    \
  __builtin_amdgcn_s_setprio(1);                          \
  _Pragma("unroll") for (int n = 0; n < 4; n++) {         \
    acc[(mlo)][n] = mfma16(a00, bf[n][0], acc[(mlo)][n]); \
    acc[(mlo) + 1][n] = mfma16(a10, bf[n][0], acc[(mlo) + 1][n]); \
    acc[(mlo)][n] = mfma16(a01, bf[n][1], acc[(mlo)][n]); \
    acc[(mlo) + 1][n] = mfma16(a11, bf[n][1], acc[(mlo) + 1][n]); \
  }                                                       \
  __builtin_amdgcn_s_setprio(0);

    // ---- P0 ----
#pragma unroll
    for (int n = 0; n < 4; n++) { bf[n][0] = LDB(cur, n, 0); bf[n][1] = LDB(cur, n, 1); }
    a00 = LDA(cur, 0, 0); a01 = LDA(cur, 0, 1); a10 = LDA(cur, 1, 0); a11 = LDA(cur, 1, 1);
    if (st) { STAGE_B(nxt, 0, kn); STAGE_B(nxt, 1, kn); }
    __builtin_amdgcn_s_barrier();
    MFMA_PAIR(0)
    __builtin_amdgcn_s_barrier();
    // ---- P1 ----
    a00 = LDA(cur, 2, 0); a01 = LDA(cur, 2, 1); a10 = LDA(cur, 3, 0); a11 = LDA(cur, 3, 1);
    if (st) { STAGE_B(nxt, 2, kn); STAGE_B(nxt, 3, kn); }
    asm volatile("s_waitcnt vmcnt(4)" ::: "memory");
    __builtin_amdgcn_s_barrier();
    MFMA_PAIR(2)
    __builtin_amdgcn_s_barrier();
    // ---- P2 ----
    a00 = LDA(cur, 4, 0); a01 = LDA(cur, 4, 1); a10 = LDA(cur, 5, 0); a11 = LDA(cur, 5, 1);
    if (st) { STAGE_A(nxt, 0, kn); STAGE_A(nxt, 2, kn); }
    __builtin_amdgcn_s_barrier();
    MFMA_PAIR(4)
    __builtin_amdgcn_s_barrier();
    // ---- P3 ----
    a00 = LDA(cur, 6, 0); a01 = LDA(cur, 6, 1); a10 = LDA(cur, 7, 0); a11 = LDA(cur, 7, 1);
    if (st) { STAGE_A(nxt, 1, kn); STAGE_A(nxt, 3, kn); }
    asm volatile("s_waitcnt vmcnt(2)" ::: "memory");
    __builtin_amdgcn_s_barrier();
    MFMA_PAIR(6)
    __builtin_amdgcn_s_barrier();
#undef MFMA_PAIR
  }

  // epilogue
#pragma unroll
  for (int m = 0; m < 8; m++)
#pragma unroll
    for (int n = 0; n < 4; n++)
#pragma unroll
      for (int r = 0; r < 4; r++)
        C[(size_t)(m0 + wm * 128 + m * 16 + g4 * 4 + r) * N + n0 + wn * 64 + n * 16 + c] =
            acc[m][n][r];
#undef STAGE_A
#undef STAGE_B
#undef LDA
#undef LDB
}

// ---------------- Flash attention: pair-balanced causal schedule, no merge ----------------
__global__ __launch_bounds__(256, 2) void attn32_kernel(const unsigned short* __restrict__ Q,
                                                        const unsigned short* __restrict__ K2,
                                                        const unsigned short* __restrict__ V2,
                                                        unsigned short* __restrict__ O) {
  int t = threadIdx.x;
  int lane = t & 63, wid = t >> 6;
  int l31 = lane & 31, hi = lane >> 5;
  int bh = blockIdx.y;
  int b = bh >> 4, h = bh & 15, kvh = h >> 2;
  int bk = b * NKV + kvh;

  int pidx = blockIdx.x * 2 + (wid >> 1);       // pair index 0..31
  int tw = (wid & 1) ? (63 - pidx) : pidx;      // this wave's q-tile
  int qw = tw * 32;

  const unsigned short* Qp = Q + ((size_t)(b * NH + h) * S_ + qw) * HD + (size_t)l31 * HD + hi * 8;
  const unsigned short* Kp = K2 + (((size_t)bk * 16 + hi) * S_ + l31) * 8;
  const unsigned short* Vp = V2 + (((size_t)bk * 256 + hi) * 128 + l31) * 8;

  bf16x8 qf[8];
#pragma unroll
  for (int kk = 0; kk < 8; kk++)
    qf[kk] = as_bf(*reinterpret_cast<const us8v*>(Qp + kk * 16));

  f32x16 oacc[4] = {};
  float mrow = -1e30f, lsum = 0.0f;

  bf16x8 kA[8], kB[8];

  auto loadK = [&](bf16x8(&kf)[8], int kv) {
    const unsigned short* kp = Kp + (size_t)kv * 8;
#pragma unroll
    for (int kk = 0; kk < 8; kk++)
      kf[kk] = as_bf(*reinterpret_cast<const us8v*>(kp + (size_t)kk * 2 * S_ * 8));
  };

  auto step = [&](bf16x8(&kf)[8], bf16x8(&kn)[8], int kv0) {
    bf16x8 vf[8];
    const unsigned short* vp = Vp + (size_t)kv0 * 128;
#pragma unroll
    for (int dt = 0; dt < 4; dt++) {
      vf[2 * dt] = as_bf(*reinterpret_cast<const us8v*>(vp + dt * 256));
      vf[2 * dt + 1] = as_bf(*reinterpret_cast<const us8v*>(vp + 2048 + dt * 256));
    }
    if (kv0 + 32 <= qw) loadK(kn, kv0 + 32);

    f32x16 sa = {}, sb = {};
    __builtin_amdgcn_s_setprio(1);
#pragma unroll
    for (int kk = 0; kk < 4; kk++) {
      sa = mfma32(kf[2 * kk], qf[2 * kk], sa);
      sb = mfma32(kf[2 * kk + 1], qf[2 * kk + 1], sb);
    }
    __builtin_amdgcn_s_setprio(0);
    f32x16 s = sa + sb;

    if (kv0 == qw) {  // diagonal tile: causal mask
      int qg = qw + l31;
#pragma unroll
      for (int r = 0; r < 16; r++) {
        int kvg = kv0 + (r & 3) + 8 * (r >> 2) + 4 * hi;
        if (kvg > qg) s[r] = -1e30f;
      }
    }

    float pm = fmaxf(s[0], s[1]);
#pragma unroll
    for (int r = 2; r < 16; r++) pm = fmaxf(pm, s[r]);
    pm = fmaxf(pm, __shfl_xor(pm, 32));

    bool nore = __all(pm <= mrow + 8.0f) != 0;  // defer-max (T13), wave-uniform
    float mn = nore ? mrow : fmaxf(mrow, pm);
    float part = 0.0f;
    uint32_t w[8];
#pragma unroll
    for (int jj = 0; jj < 8; jj++) {
      float e0 = __expf(s[2 * jj] - mn);
      float e1 = __expf(s[2 * jj + 1] - mn);
      part += e0 + e1;
      w[jj] = pk2(e0, e1);
    }
    part += __shfl_xor(part, 32);
    if (nore) {
      lsum += part;
    } else {
      float alpha = __expf(mrow - mn);  // per q-row l31
      lsum = lsum * alpha + part;
      mrow = mn;
#pragma unroll
      for (int r = 0; r < 16; r++) {
        float af = __shfl(alpha, (r & 3) + 8 * (r >> 2) + 4 * hi);
#pragma unroll
        for (int dt = 0; dt < 4; dt++) oacc[dt][r] *= af;
      }
    }

    uint32_t sw[8];
#pragma unroll
    for (int jj = 0; jj < 8; jj++) sw[jj] = __shfl_xor(w[jj], 32);
    union { uint32_t u[4]; bf16x8 v; } pa0, pa1;
    if (hi == 0) {
      pa0.u[0] = w[0]; pa0.u[1] = w[1]; pa0.u[2] = sw[0]; pa0.u[3] = sw[1];
      pa1.u[0] = w[4]; pa1.u[1] = w[5]; pa1.u[2] = sw[4]; pa1.u[3] = sw[5];
    } else {
      pa0.u[0] = sw[2]; pa0.u[1] = sw[3]; pa0.u[2] = w[2]; pa0.u[3] = w[3];
      pa1.u[0] = sw[6]; pa1.u[1] = sw[7]; pa1.u[2] = w[6]; pa1.u[3] = w[7];
    }

    __builtin_amdgcn_s_setprio(1);
#pragma unroll
    for (int dt = 0; dt < 4; dt++) {
      oacc[dt] = mfma32(pa0.v, vf[2 * dt], oacc[dt]);
      oacc[dt] = mfma32(pa1.v, vf[2 * dt + 1], oacc[dt]);
    }
    __builtin_amdgcn_s_setprio(0);
  };

  loadK(kA, 0);
  int kv0 = 0;
  while (true) {
    step(kA, kB, kv0);
    kv0 += 32;
    if (kv0 > qw) break;
    step(kB, kA, kv0);
    kv0 += 32;
    if (kv0 > qw) break;
  }

  // ---- epilogue: O[q=crow(r,hi)][d=dt*32+l31] ----
  float il = 1.0f / lsum;
  unsigned short* Op = O + ((size_t)b * S_ + qw) * D_ + h * HD;
#pragma unroll
  for (int r = 0; r < 16; r++) {
    int row = (r & 3) + 8 * (r >> 2) + 4 * hi;
    float sc = __shfl(il, row);
#pragma unroll
    for (int dt = 0; dt < 4; dt++)
      Op[(size_t)row * D_ + dt * 32 + l31] = f2b(oacc[dt][r] * sc);
  }
}

extern "C" void kernel_launch(void* const* d_in, const int* in_sizes, int n_in, void* d_out,
                              int out_size, void* d_ws, size_t ws_size, hipStream_t stream) {
  const float* x = (const float*)d_in[0];
  const float* w_qkv = (const float*)d_in[1];
  const float* w_o = (const float*)d_in[2];
  float* out = (float*)d_out;

  char* ws = (char*)d_ws;
  size_t off = 0;
  auto alloc = [&](size_t bytes) -> void* {
    void* p = ws + off;
    off += (bytes + 255) & ~(size_t)255;
    return p;
  };
  const size_t nx = (size_t)B_ * S_ * D_;
  const size_t nwqkv = (size_t)QKV_O * D_;
  const size_t nwo = (size_t)D_ * D_;
  unsigned short* xb = (unsigned short*)alloc(nx * 2);
  unsigned short* wqkvb = (unsigned short*)alloc(nwqkv * 2);
  unsigned short* wob = (unsigned short*)alloc(nwo * 2);
  float* qkv = (float*)alloc((size_t)B_ * S_ * QKV_O * 4);
  unsigned short* Qb = (unsigned short*)alloc((size_t)B_ * NH * S_ * HD * 2);
  unsigned short* K2b = (unsigned short*)alloc((size_t)B_ * NKV * S_ * HD * 2);
  unsigned short* V2b = (unsigned short*)alloc((size_t)B_ * NKV * HD * S_ * 2);
  unsigned short* attnb = (unsigned short*)alloc((size_t)B_ * S_ * D_ * 2);
  float* cs = (float*)alloc((size_t)S_ * 64 * 4);
  float* sn = (float*)alloc((size_t)S_ * 64 * 4);

  f2b_kernel<<<dim3((nx / 4 + 255) / 256), 256, 0, stream>>>(x, xb, nx / 4);
  f2b_kernel<<<dim3((nwqkv / 4 + 255) / 256), 256, 0, stream>>>(w_qkv, wqkvb, nwqkv / 4);
  f2b_kernel<<<dim3((nwo / 4 + 255) / 256), 256, 0, stream>>>(w_o, wob, nwo / 4);
  rope_table_kernel<<<dim3((S_ * 64 + 255) / 256), 256, 0, stream>>>(cs, sn);

  gemm8p_kernel<<<dim3(QKV_O / 256, (B_ * S_) / 256), 512, 0, stream>>>(xb, wqkvb, qkv,
                                                                        B_ * S_, QKV_O, D_);

  rope_qk_kernel<<<dim3((B_ * S_ * 20 * 64 + 255) / 256), 256, 0, stream>>>(qkv, cs, sn, Qb, K2b);
  v8_kernel<<<dim3(S_ / 8, B_ * NKV), 128, 0, stream>>>(qkv, V2b);

  attn32_kernel<<<dim3(16, 32), 256, 0, stream>>>(Qb, K2b, V2b, attnb);

  gemm_bt_kernel<<<dim3(D_ / 128, (B_ * S_) / 128), 256, 0, stream>>>(attnb, wob, out,
                                                                      B_ * S_, D_, D_);
}

// Round 10
// 220.745 us; speedup vs baseline: 1.3417x; 1.0182x over previous
//
#include <hip/hip_runtime.h>
#include <hip/hip_bf16.h>
#include <cstdint>
#include <cstddef>

typedef float f32x4 __attribute__((ext_vector_type(4)));
typedef float f32x16 __attribute__((ext_vector_type(16)));
typedef __bf16 bf16x8 __attribute__((ext_vector_type(8)));
typedef unsigned short us8v __attribute__((ext_vector_type(8)));
typedef unsigned short us4v __attribute__((ext_vector_type(4)));

constexpr int B_ = 2, S_ = 2048, D_ = 2048, NH = 16, NKV = 4, HD = 128;
constexpr int QKV_O = (NH + 2 * NKV) * HD;  // 3072

__device__ __forceinline__ unsigned short f2b(float f) {
  union { float f; uint32_t u; } v{f};
  uint32_t r = v.u + 0x7fffu + ((v.u >> 16) & 1u);  // RNE
  return (unsigned short)(r >> 16);
}

__device__ __forceinline__ uint32_t pk2(float a, float b) {
  union { __bf16 h[2]; uint32_t u; } v;
  v.h[0] = (__bf16)a; v.h[1] = (__bf16)b;
  return v.u;
}

__device__ __forceinline__ bf16x8 as_bf(us8v x) {
  union { us8v u; bf16x8 b; } v; v.u = x; return v.b;
}

__device__ __forceinline__ f32x4 mfma16(bf16x8 a, bf16x8 b, f32x4 c) {
  return __builtin_amdgcn_mfma_f32_16x16x32_bf16(a, b, c, 0, 0, 0);
}
__device__ __forceinline__ f32x16 mfma32(bf16x8 a, bf16x8 b, f32x16 c) {
  return __builtin_amdgcn_mfma_f32_32x32x16_bf16(a, b, c, 0, 0, 0);
}

// async global->LDS, 16B per lane; LDS dest = wave-uniform base + lane*16
__device__ __forceinline__ void gload_lds16(const unsigned short* g, unsigned short* l) {
  __builtin_amdgcn_global_load_lds(
      (const __attribute__((address_space(1))) unsigned int*)(uintptr_t)g,
      (__attribute__((address_space(3))) unsigned int*)(uintptr_t)l, 16, 0, 0);
}

// ---------------- f32 -> bf16 conversion (vectorized) ----------------
__global__ void f2b_kernel(const float* __restrict__ in, unsigned short* __restrict__ out, int n4) {
  int i = blockIdx.x * blockDim.x + threadIdx.x;
  if (i >= n4) return;
  float4 v = reinterpret_cast<const float4*>(in)[i];
  us4v o;
  o[0] = f2b(v.x); o[1] = f2b(v.y); o[2] = f2b(v.z); o[3] = f2b(v.w);
  reinterpret_cast<us4v*>(out)[i] = o;
}

// ---------------- RoPE cos/sin table: [S][64] ----------------
__global__ void rope_table_kernel(float* __restrict__ cs, float* __restrict__ sn) {
  int idx = blockIdx.x * blockDim.x + threadIdx.x;
  if (idx >= S_ * 64) return;
  int t = idx >> 6, i = idx & 63;
  float inv = __expf(-((float)(2 * i) / 128.0f) * 9.210340371976184f);
  float fr = (float)t * inv;
  cs[idx] = cosf(fr);
  sn[idx] = sinf(fr);
}

// ---------------- RoPE apply; Q -> [b,h,s,d] (pre-scaled by scale*log2e), K -> K2 ----------------
__global__ void rope_qk_kernel(const float* __restrict__ qkv, const float* __restrict__ cs,
                               const float* __restrict__ sn, unsigned short* __restrict__ Q,
                               unsigned short* __restrict__ K2) {
  int idx = blockIdx.x * blockDim.x + threadIdx.x;
  if (idx >= B_ * S_ * 20 * 64) return;
  int pr = idx & 63;
  int tmp = idx >> 6;
  int hh = tmp % 20; tmp /= 20;
  int s = tmp % S_;
  int b = tmp / S_;
  int off = (hh < 16) ? hh * HD : NH * HD + (hh - 16) * HD;
  float2 v = *reinterpret_cast<const float2*>(qkv + (size_t)(b * S_ + s) * QKV_O + off + 2 * pr);
  float c0 = cs[s * 64 + pr], s0 = sn[s * 64 + pr];
  // fold attn scale AND log2(e) into Q: softmax runs in exp2 domain
  float mult = (hh < 16) ? 0.12751744f : 1.0f;
  float o0 = (v.x * c0 - v.y * s0) * mult;
  float o1 = (v.x * s0 + v.y * c0) * mult;
  unsigned int packed = (unsigned)f2b(o0) | ((unsigned)f2b(o1) << 16);
  if (hh < 16) {
    *reinterpret_cast<unsigned*>(Q + (((size_t)(b * NH + hh) * S_ + s) * HD + 2 * pr)) = packed;
  } else {
    int bk = b * NKV + (hh - 16);
    size_t a = (((size_t)bk * 16 + (pr >> 2)) * S_ + s) * 8 + (pr & 3) * 2;
    *reinterpret_cast<unsigned*>(K2 + a) = packed;
  }
}

// ---------------- V pack: qkv f32 -> V2 bf16 [bk][s/8][d=128][8] ----------------
__global__ __launch_bounds__(128) void v8_kernel(const float* __restrict__ qkv,
                                                 unsigned short* __restrict__ V2) {
  int d = threadIdx.x;          // 0..127
  int g = blockIdx.x;           // s-group 0..255
  int bk = blockIdx.y;          // b*4+kvh
  const float* src = qkv + (size_t)((bk >> 2) * S_ + g * 8) * QKV_O + (NH + NKV) * HD +
                     (bk & 3) * HD + d;
  us8v o;
#pragma unroll
  for (int j = 0; j < 8; j++) o[j] = f2b(src[(size_t)j * QKV_O]);
  *reinterpret_cast<us8v*>(V2 + (((size_t)bk * 256 + g) * 128 + d) * 8) = o;
}

// ---------------- bf16 GEMM (m97 2-phase): C[M,N] = A[M,K] * B[N,K]^T ----------------
__global__ __launch_bounds__(256) void gemm_bt_kernel(const unsigned short* __restrict__ A,
                                                      const unsigned short* __restrict__ Bm,
                                                      float* __restrict__ C, int M, int N, int K) {
  __shared__ unsigned short As[128 * 32];
  __shared__ unsigned short Bs[128 * 32];
  int t = threadIdx.x;
  int lane = t & 63, wid = t >> 6;
  int wr = wid >> 1, wc = wid & 1;
  int g = lane >> 4, c = lane & 15;
  int m0 = blockIdx.y * 128, n0 = blockIdx.x * 128;

  int r0 = wid * 32 + (lane >> 2);
  int cc = (lane & 3) * 8;
  const unsigned short* pa = A + (size_t)(m0 + r0) * K + cc;
  const unsigned short* pb = Bm + (size_t)(n0 + r0) * K + cc;
  unsigned short* lA = As + wid * 1024;
  unsigned short* lB = Bs + wid * 1024;

  f32x4 acc[4][4] = {};
  for (int k0 = 0; k0 < K; k0 += 32) {
    gload_lds16(pa + k0, lA);
    gload_lds16(pa + (size_t)16 * K + k0, lA + 512);
    gload_lds16(pb + k0, lB);
    gload_lds16(pb + (size_t)16 * K + k0, lB + 512);
    __syncthreads();
    bf16x8 af[4], bfv[4];
#pragma unroll
    for (int m = 0; m < 4; m++)
      af[m] = as_bf(*reinterpret_cast<const us8v*>(&As[(wr * 64 + m * 16 + c) * 32 + g * 8]));
#pragma unroll
    for (int n = 0; n < 4; n++)
      bfv[n] = as_bf(*reinterpret_cast<const us8v*>(&Bs[(wc * 64 + n * 16 + c) * 32 + g * 8]));
#pragma unroll
    for (int m = 0; m < 4; m++)
#pragma unroll
      for (int n = 0; n < 4; n++) acc[m][n] = mfma16(af[m], bfv[n], acc[m][n]);
    __syncthreads();
  }
#pragma unroll
  for (int m = 0; m < 4; m++)
#pragma unroll
    for (int n = 0; n < 4; n++)
#pragma unroll
      for (int r = 0; r < 4; r++)
        C[(size_t)(m0 + wr * 64 + m * 16 + g * 4 + r) * N + n0 + wc * 64 + n * 16 + c] =
            acc[m][n][r];
}

// ---------------- bf16 GEMM (256x256 8-phase, T2+T3+T4+T5): C = A * B^T ----------------
__global__ __launch_bounds__(512, 2) void gemm8p_kernel(const unsigned short* __restrict__ A,
                                                        const unsigned short* __restrict__ Bm,
                                                        float* __restrict__ C, int M, int N,
                                                        int K) {
  __shared__ unsigned short LDS[65536];  // A: [2][16384], B: +32768
  const int t = threadIdx.x;
  const int lane = t & 63, wid = t >> 6;
  const int wm = wid >> 2, wn = wid & 3;
  const int c = lane & 15, g4 = lane >> 4;
  const int m0 = blockIdx.y * 256, n0 = blockIdx.x * 256;

  const int sr = t >> 3, ss = t & 7;
  const int sg = ss ^ (sr & 7);
  const unsigned short* pa = A + (size_t)(m0 + sr) * K + sg * 8;
  const unsigned short* pb = Bm + (size_t)(n0 + sr) * K + sg * 8;
  unsigned short* ldw = (unsigned short*)&LDS[wid << 9];

  f32x4 acc[8][4] = {};
  bf16x8 bf[4][2];

#define STAGE_A(buf, j, kk0) \
  gload_lds16(pa + (size_t)(64 * (j)) * K + (kk0), ldw + (buf)*16384 + (j)*4096)
#define STAGE_B(buf, j, kk0) \
  gload_lds16(pb + (size_t)(64 * (j)) * K + (kk0), ldw + 32768 + (buf)*16384 + (j)*4096)

#define LDA(buf, m, kk) \
  as_bf(*reinterpret_cast<const us8v*>( \
      &LDS[(buf)*16384 + (wm * 128 + (m)*16 + c) * 64 + ((((kk) << 2) | g4) ^ (c & 7)) * 8]))
#define LDB(buf, n, kk) \
  as_bf(*reinterpret_cast<const us8v*>( \
      &LDS[32768 + (buf)*16384 + (wn * 64 + (n)*16 + c) * 64 + ((((kk) << 2) | g4) ^ (c & 7)) * 8]))

#pragma unroll
  for (int j = 0; j < 4; j++) STAGE_B(0, j, 0);
#pragma unroll
  for (int j = 0; j < 4; j++) STAGE_A(0, j, 0);
  asm volatile("s_waitcnt vmcnt(0)" ::: "memory");
  __builtin_amdgcn_s_barrier();

  const int NT = K >> 6;
  for (int tt = 0; tt < NT; ++tt) {
    const int cur = tt & 1, nxt = cur ^ 1;
    const int kn = (tt + 1) << 6;
    const bool st = (tt + 1) < NT;
    bf16x8 a00, a01, a10, a11;

#define MFMA_PAIR(mlo)                                    \
  __builtin_amdgcn_s_setprio(1);                          \
  _Pragma("unroll") for (int n = 0; n < 4; n++) {         \
    acc[(mlo)][n] = mfma16(a00, bf[n][0], acc[(mlo)][n]); \
    acc[(mlo) + 1][n] = mfma16(a10, bf[n][0], acc[(mlo) + 1][n]); \
    acc[(mlo)][n] = mfma16(a01, bf[n][1], acc[(mlo)][n]); \
    acc[(mlo) + 1][n] = mfma16(a11, bf[n][1], acc[(mlo) + 1][n]); \
  }                                                       \
  __builtin_amdgcn_s_setprio(0);

    // ---- P0 ----
#pragma unroll
    for (int n = 0; n < 4; n++) { bf[n][0] = LDB(cur, n, 0); bf[n][1] = LDB(cur, n, 1); }
    a00 = LDA(cur, 0, 0); a01 = LDA(cur, 0, 1); a10 = LDA(cur, 1, 0); a11 = LDA(cur, 1, 1);
    if (st) { STAGE_B(nxt, 0, kn); STAGE_B(nxt, 1, kn); }
    __builtin_amdgcn_s_barrier();
    MFMA_PAIR(0)
    __builtin_amdgcn_s_barrier();
    // ---- P1 ----
    a00 = LDA(cur, 2, 0); a01 = LDA(cur, 2, 1); a10 = LDA(cur, 3, 0); a11 = LDA(cur, 3, 1);
    if (st) { STAGE_B(nxt, 2, kn); STAGE_B(nxt, 3, kn); }
    asm volatile("s_waitcnt vmcnt(4)" ::: "memory");
    __builtin_amdgcn_s_barrier();
    MFMA_PAIR(2)
    __builtin_amdgcn_s_barrier();
    // ---- P2 ----
    a00 = LDA(cur, 4, 0); a01 = LDA(cur, 4, 1); a10 = LDA(cur, 5, 0); a11 = LDA(cur, 5, 1);
    if (st) { STAGE_A(nxt, 0, kn); STAGE_A(nxt, 2, kn); }
    __builtin_amdgcn_s_barrier();
    MFMA_PAIR(4)
    __builtin_amdgcn_s_barrier();
    // ---- P3 ----
    a00 = LDA(cur, 6, 0); a01 = LDA(cur, 6, 1); a10 = LDA(cur, 7, 0); a11 = LDA(cur, 7, 1);
    if (st) { STAGE_A(nxt, 1, kn); STAGE_A(nxt, 3, kn); }
    asm volatile("s_waitcnt vmcnt(2)" ::: "memory");
    __builtin_amdgcn_s_barrier();
    MFMA_PAIR(6)
    __builtin_amdgcn_s_barrier();
#undef MFMA_PAIR
  }

#pragma unroll
  for (int m = 0; m < 8; m++)
#pragma unroll
    for (int n = 0; n < 4; n++)
#pragma unroll
      for (int r = 0; r < 4; r++)
        C[(size_t)(m0 + wm * 128 + m * 16 + g4 * 4 + r) * N + n0 + wn * 64 + n * 16 + c] =
            acc[m][n][r];
#undef STAGE_A
#undef STAGE_B
#undef LDA
#undef LDB
}

// ---------------- Flash attention: pair-balanced + XCD-grouped, exp2 softmax ----------------
// 1D grid of 512; id&7 = (b,kvh) group -> one XCD owns each 2MB KV set (L2-resident).
// Softmax in exp2 domain (Q pre-scaled by scale*log2e). P-repack via verified shfl_xor.
__global__ __launch_bounds__(256, 2) void attn32_kernel(const unsigned short* __restrict__ Q,
                                                        const unsigned short* __restrict__ K2,
                                                        const unsigned short* __restrict__ V2,
                                                        unsigned short* __restrict__ O) {
  int t = threadIdx.x;
  int lane = t & 63, wid = t >> 6;
  int l31 = lane & 31, hi = lane >> 5;

  int id = blockIdx.x;
  int g = id & 7, s5 = id >> 3;          // g = (b,kvh) group -> XCD g
  int b = g >> 2, kvh = g & 3;
  int h = kvh * 4 + (s5 & 3);
  int bk = b * NKV + kvh;
  int pidx = (s5 >> 2) * 2 + (wid >> 1);  // pair index 0..31
  int tw = (wid & 1) ? (63 - pidx) : pidx;
  int qw = tw * 32;

  const unsigned short* Qp = Q + ((size_t)(b * NH + h) * S_ + qw) * HD + (size_t)l31 * HD + hi * 8;
  const unsigned short* Kp = K2 + (((size_t)bk * 16 + hi) * S_ + l31) * 8;
  const unsigned short* Vp = V2 + (((size_t)bk * 256 + hi) * 128 + l31) * 8;

  bf16x8 qf[8];
#pragma unroll
  for (int kk = 0; kk < 8; kk++)
    qf[kk] = as_bf(*reinterpret_cast<const us8v*>(Qp + kk * 16));

  f32x16 oacc[4] = {};
  float mrow = -1e30f, lsum = 0.0f;

  bf16x8 kA[8], kB[8];

  auto loadK = [&](bf16x8(&kf)[8], int kv) {
    const unsigned short* kp = Kp + (size_t)kv * 8;
#pragma unroll
    for (int kk = 0; kk < 8; kk++)
      kf[kk] = as_bf(*reinterpret_cast<const us8v*>(kp + (size_t)kk * 2 * S_ * 8));
  };

  auto step = [&](bf16x8(&kf)[8], bf16x8(&kn)[8], int kv0) {
    bf16x8 vf[8];
    const unsigned short* vp = Vp + (size_t)kv0 * 128;
#pragma unroll
    for (int dt = 0; dt < 4; dt++) {
      vf[2 * dt] = as_bf(*reinterpret_cast<const us8v*>(vp + dt * 256));
      vf[2 * dt + 1] = as_bf(*reinterpret_cast<const us8v*>(vp + 2048 + dt * 256));
    }
    if (kv0 + 32 <= qw) loadK(kn, kv0 + 32);

    f32x16 sa = {}, sb = {};
    __builtin_amdgcn_s_setprio(1);
#pragma unroll
    for (int kk = 0; kk < 4; kk++) {
      sa = mfma32(kf[2 * kk], qf[2 * kk], sa);
      sb = mfma32(kf[2 * kk + 1], qf[2 * kk + 1], sb);
    }
    __builtin_amdgcn_s_setprio(0);
    f32x16 s = sa + sb;

    if (kv0 == qw) {  // diagonal tile: causal mask
      int qg = qw + l31;
#pragma unroll
      for (int r = 0; r < 16; r++) {
        int kvg = kv0 + (r & 3) + 8 * (r >> 2) + 4 * hi;
        if (kvg > qg) s[r] = -1e30f;
      }
    }

    float pm = fmaxf(s[0], s[1]);
#pragma unroll
    for (int r = 2; r < 16; r++) pm = fmaxf(pm, s[r]);
    pm = fmaxf(pm, __shfl_xor(pm, 32));

    bool nore = __all(pm <= mrow + 11.54f) != 0;  // defer-max, log2 units (= e^8 bound)
    float mn = nore ? mrow : fmaxf(mrow, pm);
    float part = 0.0f;
    uint32_t w[8];
#pragma unroll
    for (int jj = 0; jj < 8; jj++) {
      float e0 = __builtin_amdgcn_exp2f(s[2 * jj] - mn);
      float e1 = __builtin_amdgcn_exp2f(s[2 * jj + 1] - mn);
      part += e0 + e1;
      w[jj] = pk2(e0, e1);
    }
    part += __shfl_xor(part, 32);
    if (nore) {
      lsum += part;
    } else {
      float alpha = __builtin_amdgcn_exp2f(mrow - mn);  // per q-row l31
      lsum = lsum * alpha + part;
      mrow = mn;
#pragma unroll
      for (int r = 0; r < 16; r++) {
        float af = __shfl(alpha, (r & 3) + 8 * (r >> 2) + 4 * hi);
#pragma unroll
        for (int dt = 0; dt < 4; dt++) oacc[dt][r] *= af;
      }
    }

    // ---- P -> A-fragments via lane^32 exchange (verified through r8) ----
    uint32_t sw[8];
#pragma unroll
    for (int jj = 0; jj < 8; jj++) sw[jj] = __shfl_xor(w[jj], 32);
    union { uint32_t u[4]; bf16x8 v; } pa0, pa1;
    if (hi == 0) {
      pa0.u[0] = w[0]; pa0.u[1] = w[1]; pa0.u[2] = sw[0]; pa0.u[3] = sw[1];
      pa1.u[0] = w[4]; pa1.u[1] = w[5]; pa1.u[2] = sw[4]; pa1.u[3] = sw[5];
    } else {
      pa0.u[0] = sw[2]; pa0.u[1] = sw[3]; pa0.u[2] = w[2]; pa0.u[3] = w[3];
      pa1.u[0] = sw[6]; pa1.u[1] = sw[7]; pa1.u[2] = w[6]; pa1.u[3] = w[7];
    }

    __builtin_amdgcn_s_setprio(1);
#pragma unroll
    for (int dt = 0; dt < 4; dt++) {
      oacc[dt] = mfma32(pa0.v, vf[2 * dt], oacc[dt]);
      oacc[dt] = mfma32(pa1.v, vf[2 * dt + 1], oacc[dt]);
    }
    __builtin_amdgcn_s_setprio(0);
  };

  loadK(kA, 0);
  int kv0 = 0;
  while (true) {
    step(kA, kB, kv0);
    kv0 += 32;
    if (kv0 > qw) break;
    step(kB, kA, kv0);
    kv0 += 32;
    if (kv0 > qw) break;
  }

  // ---- epilogue: O[q=crow(r,hi)][d=dt*32+l31] ----
  float il = 1.0f / lsum;
  unsigned short* Op = O + ((size_t)b * S_ + qw) * D_ + h * HD;
#pragma unroll
  for (int r = 0; r < 16; r++) {
    int row = (r & 3) + 8 * (r >> 2) + 4 * hi;
    float sc = __shfl(il, row);
#pragma unroll
    for (int dt = 0; dt < 4; dt++)
      Op[(size_t)row * D_ + dt * 32 + l31] = f2b(oacc[dt][r] * sc);
  }
}

extern "C" void kernel_launch(void* const* d_in, const int* in_sizes, int n_in, void* d_out,
                              int out_size, void* d_ws, size_t ws_size, hipStream_t stream) {
  const float* x = (const float*)d_in[0];
  const float* w_qkv = (const float*)d_in[1];
  const float* w_o = (const float*)d_in[2];
  float* out = (float*)d_out;

  char* ws = (char*)d_ws;
  size_t off = 0;
  auto alloc = [&](size_t bytes) -> void* {
    void* p = ws + off;
    off += (bytes + 255) & ~(size_t)255;
    return p;
  };
  const size_t nx = (size_t)B_ * S_ * D_;
  const size_t nwqkv = (size_t)QKV_O * D_;
  const size_t nwo = (size_t)D_ * D_;
  unsigned short* xb = (unsigned short*)alloc(nx * 2);
  unsigned short* wqkvb = (unsigned short*)alloc(nwqkv * 2);
  unsigned short* wob = (unsigned short*)alloc(nwo * 2);
  float* qkv = (float*)alloc((size_t)B_ * S_ * QKV_O * 4);
  unsigned short* Qb = (unsigned short*)alloc((size_t)B_ * NH * S_ * HD * 2);
  unsigned short* K2b = (unsigned short*)alloc((size_t)B_ * NKV * S_ * HD * 2);
  unsigned short* V2b = (unsigned short*)alloc((size_t)B_ * NKV * HD * S_ * 2);
  unsigned short* attnb = (unsigned short*)alloc((size_t)B_ * S_ * D_ * 2);
  float* cs = (float*)alloc((size_t)S_ * 64 * 4);
  float* sn = (float*)alloc((size_t)S_ * 64 * 4);

  f2b_kernel<<<dim3((nx / 4 + 255) / 256), 256, 0, stream>>>(x, xb, nx / 4);
  f2b_kernel<<<dim3((nwqkv / 4 + 255) / 256), 256, 0, stream>>>(w_qkv, wqkvb, nwqkv / 4);
  f2b_kernel<<<dim3((nwo / 4 + 255) / 256), 256, 0, stream>>>(w_o, wob, nwo / 4);
  rope_table_kernel<<<dim3((S_ * 64 + 255) / 256), 256, 0, stream>>>(cs, sn);

  gemm8p_kernel<<<dim3(QKV_O / 256, (B_ * S_) / 256), 512, 0, stream>>>(xb, wqkvb, qkv,
                                                                        B_ * S_, QKV_O, D_);

  rope_qk_kernel<<<dim3((B_ * S_ * 20 * 64 + 255) / 256), 256, 0, stream>>>(qkv, cs, sn, Qb, K2b);
  v8_kernel<<<dim3(S_ / 8, B_ * NKV), 128, 0, stream>>>(qkv, V2b);

  attn32_kernel<<<dim3(512), 256, 0, stream>>>(Qb, K2b, V2b, attnb);

  gemm_bt_kernel<<<dim3(D_ / 128, (B_ * S_) / 128), 256, 0, stream>>>(attnb, wob, out,
                                                                      B_ * S_, D_, D_);
}

// Round 11
// 210.483 us; speedup vs baseline: 1.4071x; 1.0488x over previous
//
#include <hip/hip_runtime.h>
#include <hip/hip_bf16.h>
#include <cstdint>
#include <cstddef>

typedef float f32x4 __attribute__((ext_vector_type(4)));
typedef float f32x16 __attribute__((ext_vector_type(16)));
typedef __bf16 bf16x8 __attribute__((ext_vector_type(8)));
typedef unsigned short us8v __attribute__((ext_vector_type(8)));
typedef unsigned short us4v __attribute__((ext_vector_type(4)));

constexpr int B_ = 2, S_ = 2048, D_ = 2048, NH = 16, NKV = 4, HD = 128;
constexpr int QKV_O = (NH + 2 * NKV) * HD;  // 3072

__device__ __forceinline__ unsigned short f2b(float f) {
  union { float f; uint32_t u; } v{f};
  uint32_t r = v.u + 0x7fffu + ((v.u >> 16) & 1u);  // RNE
  return (unsigned short)(r >> 16);
}

__device__ __forceinline__ uint32_t pk2(float a, float b) {
  union { __bf16 h[2]; uint32_t u; } v;
  v.h[0] = (__bf16)a; v.h[1] = (__bf16)b;
  return v.u;
}

__device__ __forceinline__ bf16x8 as_bf(us8v x) {
  union { us8v u; bf16x8 b; } v; v.u = x; return v.b;
}

__device__ __forceinline__ f32x4 mfma16(bf16x8 a, bf16x8 b, f32x4 c) {
  return __builtin_amdgcn_mfma_f32_16x16x32_bf16(a, b, c, 0, 0, 0);
}
__device__ __forceinline__ f32x16 mfma32(bf16x8 a, bf16x8 b, f32x16 c) {
  return __builtin_amdgcn_mfma_f32_32x32x16_bf16(a, b, c, 0, 0, 0);
}

// async global->LDS, 16B per lane; LDS dest = wave-uniform base + lane*16
__device__ __forceinline__ void gload_lds16(const unsigned short* g, unsigned short* l) {
  __builtin_amdgcn_global_load_lds(
      (const __attribute__((address_space(1))) unsigned int*)(uintptr_t)g,
      (__attribute__((address_space(3))) unsigned int*)(uintptr_t)l, 16, 0, 0);
}

// ---------------- f32 -> bf16 conversion (vectorized) ----------------
__global__ void f2b_kernel(const float* __restrict__ in, unsigned short* __restrict__ out, int n4) {
  int i = blockIdx.x * blockDim.x + threadIdx.x;
  if (i >= n4) return;
  float4 v = reinterpret_cast<const float4*>(in)[i];
  us4v o;
  o[0] = f2b(v.x); o[1] = f2b(v.y); o[2] = f2b(v.z); o[3] = f2b(v.w);
  reinterpret_cast<us4v*>(out)[i] = o;
}

// ---------------- RoPE cos/sin table: [S][64] ----------------
__global__ void rope_table_kernel(float* __restrict__ cs, float* __restrict__ sn) {
  int idx = blockIdx.x * blockDim.x + threadIdx.x;
  if (idx >= S_ * 64) return;
  int t = idx >> 6, i = idx & 63;
  float inv = __expf(-((float)(2 * i) / 128.0f) * 9.210340371976184f);
  float fr = (float)t * inv;
  cs[idx] = cosf(fr);
  sn[idx] = sinf(fr);
}

// ---------------- RoPE apply; Q -> [b,h,s,d] (pre-scaled by scale*log2e), K -> K2 ----------------
__global__ void rope_qk_kernel(const float* __restrict__ qkv, const float* __restrict__ cs,
                               const float* __restrict__ sn, unsigned short* __restrict__ Q,
                               unsigned short* __restrict__ K2) {
  int idx = blockIdx.x * blockDim.x + threadIdx.x;
  if (idx >= B_ * S_ * 20 * 64) return;
  int pr = idx & 63;
  int tmp = idx >> 6;
  int hh = tmp % 20; tmp /= 20;
  int s = tmp % S_;
  int b = tmp / S_;
  int off = (hh < 16) ? hh * HD : NH * HD + (hh - 16) * HD;
  float2 v = *reinterpret_cast<const float2*>(qkv + (size_t)(b * S_ + s) * QKV_O + off + 2 * pr);
  float c0 = cs[s * 64 + pr], s0 = sn[s * 64 + pr];
  // fold attn scale AND log2(e) into Q: softmax runs in exp2 domain
  float mult = (hh < 16) ? 0.12751744f : 1.0f;
  float o0 = (v.x * c0 - v.y * s0) * mult;
  float o1 = (v.x * s0 + v.y * c0) * mult;
  unsigned int packed = (unsigned)f2b(o0) | ((unsigned)f2b(o1) << 16);
  if (hh < 16) {
    *reinterpret_cast<unsigned*>(Q + (((size_t)(b * NH + hh) * S_ + s) * HD + 2 * pr)) = packed;
  } else {
    int bk = b * NKV + (hh - 16);
    size_t a = (((size_t)bk * 16 + (pr >> 2)) * S_ + s) * 8 + (pr & 3) * 2;
    *reinterpret_cast<unsigned*>(K2 + a) = packed;
  }
}

// ---------------- V pack: qkv f32 -> V2 bf16 [bk][s/8][d=128][8] ----------------
__global__ __launch_bounds__(128) void v8_kernel(const float* __restrict__ qkv,
                                                 unsigned short* __restrict__ V2) {
  int d = threadIdx.x;          // 0..127
  int g = blockIdx.x;           // s-group 0..255
  int bk = blockIdx.y;          // b*4+kvh
  const float* src = qkv + (size_t)((bk >> 2) * S_ + g * 8) * QKV_O + (NH + NKV) * HD +
                     (bk & 3) * HD + d;
  us8v o;
#pragma unroll
  for (int j = 0; j < 8; j++) o[j] = f2b(src[(size_t)j * QKV_O]);
  *reinterpret_cast<us8v*>(V2 + (((size_t)bk * 256 + g) * 128 + d) * 8) = o;
}

// ---------------- bf16 GEMM (256x256 8-phase, T1+T2+T3+T4+T5): C = A * B^T ----------------
// 1-D grid (nwg%8==0), XCD-chunked swizzle. Counted vmcnt(4)/vmcnt(2).
__global__ __launch_bounds__(512, 2) void gemm8p_kernel(const unsigned short* __restrict__ A,
                                                        const unsigned short* __restrict__ Bm,
                                                        float* __restrict__ C, int M, int N,
                                                        int K, int nbx) {
  __shared__ unsigned short LDS[65536];  // A: [2][16384], B: +32768
  const int t = threadIdx.x;
  const int lane = t & 63, wid = t >> 6;
  const int wm = wid >> 2, wn = wid & 3;
  const int c = lane & 15, g4 = lane >> 4;
  // T1: bijective XCD swizzle (gridDim.x % 8 == 0)
  const int cpx = gridDim.x >> 3;
  const int nid = (blockIdx.x & 7) * cpx + (blockIdx.x >> 3);
  const int m0 = (nid / nbx) * 256, n0 = (nid % nbx) * 256;

  const int sr = t >> 3, ss = t & 7;
  const int sg = ss ^ (sr & 7);
  const unsigned short* pa = A + (size_t)(m0 + sr) * K + sg * 8;
  const unsigned short* pb = Bm + (size_t)(n0 + sr) * K + sg * 8;
  unsigned short* ldw = (unsigned short*)&LDS[wid << 9];

  f32x4 acc[8][4] = {};
  bf16x8 bf[4][2];

#define STAGE_A(buf, j, kk0) \
  gload_lds16(pa + (size_t)(64 * (j)) * K + (kk0), ldw + (buf)*16384 + (j)*4096)
#define STAGE_B(buf, j, kk0) \
  gload_lds16(pb + (size_t)(64 * (j)) * K + (kk0), ldw + 32768 + (buf)*16384 + (j)*4096)

#define LDA(buf, m, kk) \
  as_bf(*reinterpret_cast<const us8v*>( \
      &LDS[(buf)*16384 + (wm * 128 + (m)*16 + c) * 64 + ((((kk) << 2) | g4) ^ (c & 7)) * 8]))
#define LDB(buf, n, kk) \
  as_bf(*reinterpret_cast<const us8v*>( \
      &LDS[32768 + (buf)*16384 + (wn * 64 + (n)*16 + c) * 64 + ((((kk) << 2) | g4) ^ (c & 7)) * 8]))

#pragma unroll
  for (int j = 0; j < 4; j++) STAGE_B(0, j, 0);
#pragma unroll
  for (int j = 0; j < 4; j++) STAGE_A(0, j, 0);
  asm volatile("s_waitcnt vmcnt(0)" ::: "memory");
  __builtin_amdgcn_s_barrier();

  const int NT = K >> 6;
  for (int tt = 0; tt < NT; ++tt) {
    const int cur = tt & 1, nxt = cur ^ 1;
    const int kn = (tt + 1) << 6;
    const bool st = (tt + 1) < NT;
    bf16x8 a00, a01, a10, a11;

#define MFMA_PAIR(mlo)                                    \
  __builtin_amdgcn_s_setprio(1);                          \
  _Pragma("unroll") for (int n = 0; n < 4; n++) {         \
    acc[(mlo)][n] = mfma16(a00, bf[n][0], acc[(mlo)][n]); \
    acc[(mlo) + 1][n] = mfma16(a10, bf[n][0], acc[(mlo) + 1][n]); \
    acc[(mlo)][n] = mfma16(a01, bf[n][1], acc[(mlo)][n]); \
    acc[(mlo) + 1][n] = mfma16(a11, bf[n][1], acc[(mlo) + 1][n]); \
  }                                                       \
  __builtin_amdgcn_s_setprio(0);

    // ---- P0 ----
#pragma unroll
    for (int n = 0; n < 4; n++) { bf[n][0] = LDB(cur, n, 0); bf[n][1] = LDB(cur, n, 1); }
    a00 = LDA(cur, 0, 0); a01 = LDA(cur, 0, 1); a10 = LDA(cur, 1, 0); a11 = LDA(cur, 1, 1);
    if (st) { STAGE_B(nxt, 0, kn); STAGE_B(nxt, 1, kn); }
    __builtin_amdgcn_s_barrier();
    MFMA_PAIR(0)
    __builtin_amdgcn_s_barrier();
    // ---- P1 ----
    a00 = LDA(cur, 2, 0); a01 = LDA(cur, 2, 1); a10 = LDA(cur, 3, 0); a11 = LDA(cur, 3, 1);
    if (st) { STAGE_B(nxt, 2, kn); STAGE_B(nxt, 3, kn); }
    asm volatile("s_waitcnt vmcnt(4)" ::: "memory");
    __builtin_amdgcn_s_barrier();
    MFMA_PAIR(2)
    __builtin_amdgcn_s_barrier();
    // ---- P2 ----
    a00 = LDA(cur, 4, 0); a01 = LDA(cur, 4, 1); a10 = LDA(cur, 5, 0); a11 = LDA(cur, 5, 1);
    if (st) { STAGE_A(nxt, 0, kn); STAGE_A(nxt, 2, kn); }
    __builtin_amdgcn_s_barrier();
    MFMA_PAIR(4)
    __builtin_amdgcn_s_barrier();
    // ---- P3 ----
    a00 = LDA(cur, 6, 0); a01 = LDA(cur, 6, 1); a10 = LDA(cur, 7, 0); a11 = LDA(cur, 7, 1);
    if (st) { STAGE_A(nxt, 1, kn); STAGE_A(nxt, 3, kn); }
    asm volatile("s_waitcnt vmcnt(2)" ::: "memory");
    __builtin_amdgcn_s_barrier();
    MFMA_PAIR(6)
    __builtin_amdgcn_s_barrier();
#undef MFMA_PAIR
  }

#pragma unroll
  for (int m = 0; m < 8; m++)
#pragma unroll
    for (int n = 0; n < 4; n++)
#pragma unroll
      for (int r = 0; r < 4; r++)
        C[(size_t)(m0 + wm * 128 + m * 16 + g4 * 4 + r) * N + n0 + wn * 64 + n * 16 + c] =
            acc[m][n][r];
#undef STAGE_A
#undef STAGE_B
#undef LDA
#undef LDB
}

// ---------------- bf16 GEMM (256x128 8-phase, f32 C): out-proj, 100% CU fill ----------------
// 8 waves 2Mx4N, per-wave 128x32. LDS 96KB: A[2][16384], B[2][8192].
// Stage per iter: P0:B0 P1:B1 P2:A0,A2 P3:A1,A3; vmcnt(2) at P1 (A1,A3 retire
// before P2 reads) and at P3 (B0,B1,A0,A2 retire before next P0/P1). Never 0 in loop.
__global__ __launch_bounds__(512, 2) void gemm8pn_kernel(const unsigned short* __restrict__ A,
                                                         const unsigned short* __restrict__ Bm,
                                                         float* __restrict__ C, int M, int N,
                                                         int K, int nbx) {
  __shared__ unsigned short LDS[49152];  // A: [2][16384]; B at 32768 + [2][8192]
  const int t = threadIdx.x;
  const int lane = t & 63, wid = t >> 6;
  const int wm = wid >> 2, wn = wid & 3;
  const int c = lane & 15, g4 = lane >> 4;
  const int cpx = gridDim.x >> 3;
  const int nid = (blockIdx.x & 7) * cpx + (blockIdx.x >> 3);
  const int m0 = (nid / nbx) * 256, n0 = (nid % nbx) * 128;

  const int sr = t >> 3, ss = t & 7;
  const int sg = ss ^ (sr & 7);
  const unsigned short* pa = A + (size_t)(m0 + sr) * K + sg * 8;
  const unsigned short* pb = Bm + (size_t)(n0 + sr) * K + sg * 8;
  unsigned short* ldw = (unsigned short*)&LDS[wid << 9];

  f32x4 acc[8][2] = {};
  bf16x8 bf[2][2];

#define STAGE_A(buf, j, kk0) \
  gload_lds16(pa + (size_t)(64 * (j)) * K + (kk0), ldw + (buf)*16384 + (j)*4096)
#define STAGE_B(buf, j, kk0) \
  gload_lds16(pb + (size_t)(64 * (j)) * K + (kk0), ldw + 32768 + (buf)*8192 + (j)*4096)

#define LDA(buf, m, kk) \
  as_bf(*reinterpret_cast<const us8v*>( \
      &LDS[(buf)*16384 + (wm * 128 + (m)*16 + c) * 64 + ((((kk) << 2) | g4) ^ (c & 7)) * 8]))
#define LDB(buf, n, kk) \
  as_bf(*reinterpret_cast<const us8v*>( \
      &LDS[32768 + (buf)*8192 + (wn * 32 + (n)*16 + c) * 64 + ((((kk) << 2) | g4) ^ (c & 7)) * 8]))

  STAGE_B(0, 0, 0); STAGE_B(0, 1, 0);
#pragma unroll
  for (int j = 0; j < 4; j++) STAGE_A(0, j, 0);
  asm volatile("s_waitcnt vmcnt(0)" ::: "memory");
  __builtin_amdgcn_s_barrier();

  const int NT = K >> 6;
  for (int tt = 0; tt < NT; ++tt) {
    const int cur = tt & 1, nxt = cur ^ 1;
    const int kn = (tt + 1) << 6;
    const bool st = (tt + 1) < NT;
    bf16x8 a00, a01, a10, a11;

#define MFMA_PAIR(mlo)                                    \
  __builtin_amdgcn_s_setprio(1);                          \
  _Pragma("unroll") for (int n = 0; n < 2; n++) {         \
    acc[(mlo)][n] = mfma16(a00, bf[n][0], acc[(mlo)][n]); \
    acc[(mlo) + 1][n] = mfma16(a10, bf[n][0], acc[(mlo) + 1][n]); \
    acc[(mlo)][n] = mfma16(a01, bf[n][1], acc[(mlo)][n]); \
    acc[(mlo) + 1][n] = mfma16(a11, bf[n][1], acc[(mlo) + 1][n]); \
  }                                                       \
  __builtin_amdgcn_s_setprio(0);

    // ---- P0 ----
#pragma unroll
    for (int n = 0; n < 2; n++) { bf[n][0] = LDB(cur, n, 0); bf[n][1] = LDB(cur, n, 1); }
    a00 = LDA(cur, 0, 0); a01 = LDA(cur, 0, 1); a10 = LDA(cur, 1, 0); a11 = LDA(cur, 1, 1);
    if (st) STAGE_B(nxt, 0, kn);
    __builtin_amdgcn_s_barrier();
    MFMA_PAIR(0)
    __builtin_amdgcn_s_barrier();
    // ---- P1 ----
    a00 = LDA(cur, 2, 0); a01 = LDA(cur, 2, 1); a10 = LDA(cur, 3, 0); a11 = LDA(cur, 3, 1);
    if (st) STAGE_B(nxt, 1, kn);
    asm volatile("s_waitcnt vmcnt(2)" ::: "memory");
    __builtin_amdgcn_s_barrier();
    MFMA_PAIR(2)
    __builtin_amdgcn_s_barrier();
    // ---- P2 ----
    a00 = LDA(cur, 4, 0); a01 = LDA(cur, 4, 1); a10 = LDA(cur, 5, 0); a11 = LDA(cur, 5, 1);
    if (st) { STAGE_A(nxt, 0, kn); STAGE_A(nxt, 2, kn); }
    __builtin_amdgcn_s_barrier();
    MFMA_PAIR(4)
    __builtin_amdgcn_s_barrier();
    // ---- P3 ----
    a00 = LDA(cur, 6, 0); a01 = LDA(cur, 6, 1); a10 = LDA(cur, 7, 0); a11 = LDA(cur, 7, 1);
    if (st) { STAGE_A(nxt, 1, kn); STAGE_A(nxt, 3, kn); }
    asm volatile("s_waitcnt vmcnt(2)" ::: "memory");
    __builtin_amdgcn_s_barrier();
    MFMA_PAIR(6)
    __builtin_amdgcn_s_barrier();
#undef MFMA_PAIR
  }

#pragma unroll
  for (int m = 0; m < 8; m++)
#pragma unroll
    for (int n = 0; n < 2; n++)
#pragma unroll
      for (int r = 0; r < 4; r++)
        C[(size_t)(m0 + wm * 128 + m * 16 + g4 * 4 + r) * N + n0 + wn * 32 + n * 16 + c] =
            acc[m][n][r];
#undef STAGE_A
#undef STAGE_B
#undef LDA
#undef LDB
}

// ---------------- Flash attention: pair-balanced + XCD-grouped, exp2 softmax ----------------
__global__ __launch_bounds__(256, 2) void attn32_kernel(const unsigned short* __restrict__ Q,
                                                        const unsigned short* __restrict__ K2,
                                                        const unsigned short* __restrict__ V2,
                                                        unsigned short* __restrict__ O) {
  int t = threadIdx.x;
  int lane = t & 63, wid = t >> 6;
  int l31 = lane & 31, hi = lane >> 5;

  int id = blockIdx.x;
  int g = id & 7, s5 = id >> 3;          // g = (b,kvh) group -> XCD g
  int b = g >> 2, kvh = g & 3;
  int h = kvh * 4 + (s5 & 3);
  int bk = b * NKV + kvh;
  int pidx = (s5 >> 2) * 2 + (wid >> 1);  // pair index 0..31
  int tw = (wid & 1) ? (63 - pidx) : pidx;
  int qw = tw * 32;

  const unsigned short* Qp = Q + ((size_t)(b * NH + h) * S_ + qw) * HD + (size_t)l31 * HD + hi * 8;
  const unsigned short* Kp = K2 + (((size_t)bk * 16 + hi) * S_ + l31) * 8;
  const unsigned short* Vp = V2 + (((size_t)bk * 256 + hi) * 128 + l31) * 8;

  bf16x8 qf[8];
#pragma unroll
  for (int kk = 0; kk < 8; kk++)
    qf[kk] = as_bf(*reinterpret_cast<const us8v*>(Qp + kk * 16));

  f32x16 oacc[4] = {};
  float mrow = -1e30f, lsum = 0.0f;

  bf16x8 kA[8], kB[8];

  auto loadK = [&](bf16x8(&kf)[8], int kv) {
    const unsigned short* kp = Kp + (size_t)kv * 8;
#pragma unroll
    for (int kk = 0; kk < 8; kk++)
      kf[kk] = as_bf(*reinterpret_cast<const us8v*>(kp + (size_t)kk * 2 * S_ * 8));
  };

  auto step = [&](bf16x8(&kf)[8], bf16x8(&kn)[8], int kv0) {
    bf16x8 vf[8];
    const unsigned short* vp = Vp + (size_t)kv0 * 128;
#pragma unroll
    for (int dt = 0; dt < 4; dt++) {
      vf[2 * dt] = as_bf(*reinterpret_cast<const us8v*>(vp + dt * 256));
      vf[2 * dt + 1] = as_bf(*reinterpret_cast<const us8v*>(vp + 2048 + dt * 256));
    }
    if (kv0 + 32 <= qw) loadK(kn, kv0 + 32);

    f32x16 sa = {}, sb = {};
    __builtin_amdgcn_s_setprio(1);
#pragma unroll
    for (int kk = 0; kk < 4; kk++) {
      sa = mfma32(kf[2 * kk], qf[2 * kk], sa);
      sb = mfma32(kf[2 * kk + 1], qf[2 * kk + 1], sb);
    }
    __builtin_amdgcn_s_setprio(0);
    f32x16 s = sa + sb;

    if (kv0 == qw) {  // diagonal tile: causal mask
      int qg = qw + l31;
#pragma unroll
      for (int r = 0; r < 16; r++) {
        int kvg = kv0 + (r & 3) + 8 * (r >> 2) + 4 * hi;
        if (kvg > qg) s[r] = -1e30f;
      }
    }

    float pm = fmaxf(s[0], s[1]);
#pragma unroll
    for (int r = 2; r < 16; r++) pm = fmaxf(pm, s[r]);
    pm = fmaxf(pm, __shfl_xor(pm, 32));

    bool nore = __all(pm <= mrow + 11.54f) != 0;  // defer-max, log2 units
    float mn = nore ? mrow : fmaxf(mrow, pm);
    float part = 0.0f;
    uint32_t w[8];
#pragma unroll
    for (int jj = 0; jj < 8; jj++) {
      float e0 = __builtin_amdgcn_exp2f(s[2 * jj] - mn);
      float e1 = __builtin_amdgcn_exp2f(s[2 * jj + 1] - mn);
      part += e0 + e1;
      w[jj] = pk2(e0, e1);
    }
    part += __shfl_xor(part, 32);
    if (nore) {
      lsum += part;
    } else {
      float alpha = __builtin_amdgcn_exp2f(mrow - mn);  // per q-row l31
      lsum = lsum * alpha + part;
      mrow = mn;
#pragma unroll
      for (int r = 0; r < 16; r++) {
        float af = __shfl(alpha, (r & 3) + 8 * (r >> 2) + 4 * hi);
#pragma unroll
        for (int dt = 0; dt < 4; dt++) oacc[dt][r] *= af;
      }
    }

    // ---- P -> A-fragments via lane^32 exchange ----
    uint32_t sw[8];
#pragma unroll
    for (int jj = 0; jj < 8; jj++) sw[jj] = __shfl_xor(w[jj], 32);
    union { uint32_t u[4]; bf16x8 v; } pa0, pa1;
    if (hi == 0) {
      pa0.u[0] = w[0]; pa0.u[1] = w[1]; pa0.u[2] = sw[0]; pa0.u[3] = sw[1];
      pa1.u[0] = w[4]; pa1.u[1] = w[5]; pa1.u[2] = sw[4]; pa1.u[3] = sw[5];
    } else {
      pa0.u[0] = sw[2]; pa0.u[1] = sw[3]; pa0.u[2] = w[2]; pa0.u[3] = w[3];
      pa1.u[0] = sw[6]; pa1.u[1] = sw[7]; pa1.u[2] = w[6]; pa1.u[3] = w[7];
    }

    __builtin_amdgcn_s_setprio(1);
#pragma unroll
    for (int dt = 0; dt < 4; dt++) {
      oacc[dt] = mfma32(pa0.v, vf[2 * dt], oacc[dt]);
      oacc[dt] = mfma32(pa1.v, vf[2 * dt + 1], oacc[dt]);
    }
    __builtin_amdgcn_s_setprio(0);
  };

  loadK(kA, 0);
  int kv0 = 0;
  while (true) {
    step(kA, kB, kv0);
    kv0 += 32;
    if (kv0 > qw) break;
    step(kB, kA, kv0);
    kv0 += 32;
    if (kv0 > qw) break;
  }

  // ---- epilogue: O[q=crow(r,hi)][d=dt*32+l31] ----
  float il = 1.0f / lsum;
  unsigned short* Op = O + ((size_t)b * S_ + qw) * D_ + h * HD;
#pragma unroll
  for (int r = 0; r < 16; r++) {
    int row = (r & 3) + 8 * (r >> 2) + 4 * hi;
    float sc = __shfl(il, row);
#pragma unroll
    for (int dt = 0; dt < 4; dt++)
      Op[(size_t)row * D_ + dt * 32 + l31] = f2b(oacc[dt][r] * sc);
  }
}

extern "C" void kernel_launch(void* const* d_in, const int* in_sizes, int n_in, void* d_out,
                              int out_size, void* d_ws, size_t ws_size, hipStream_t stream) {
  const float* x = (const float*)d_in[0];
  const float* w_qkv = (const float*)d_in[1];
  const float* w_o = (const float*)d_in[2];
  float* out = (float*)d_out;

  char* ws = (char*)d_ws;
  size_t off = 0;
  auto alloc = [&](size_t bytes) -> void* {
    void* p = ws + off;
    off += (bytes + 255) & ~(size_t)255;
    return p;
  };
  const size_t nx = (size_t)B_ * S_ * D_;
  const size_t nwqkv = (size_t)QKV_O * D_;
  const size_t nwo = (size_t)D_ * D_;
  unsigned short* xb = (unsigned short*)alloc(nx * 2);
  unsigned short* wqkvb = (unsigned short*)alloc(nwqkv * 2);
  unsigned short* wob = (unsigned short*)alloc(nwo * 2);
  float* qkv = (float*)alloc((size_t)B_ * S_ * QKV_O * 4);
  unsigned short* Qb = (unsigned short*)alloc((size_t)B_ * NH * S_ * HD * 2);
  unsigned short* K2b = (unsigned short*)alloc((size_t)B_ * NKV * S_ * HD * 2);
  unsigned short* V2b = (unsigned short*)alloc((size_t)B_ * NKV * HD * S_ * 2);
  unsigned short* attnb = (unsigned short*)alloc((size_t)B_ * S_ * D_ * 2);
  float* cs = (float*)alloc((size_t)S_ * 64 * 4);
  float* sn = (float*)alloc((size_t)S_ * 64 * 4);

  f2b_kernel<<<dim3((nx / 4 + 255) / 256), 256, 0, stream>>>(x, xb, nx / 4);
  f2b_kernel<<<dim3((nwqkv / 4 + 255) / 256), 256, 0, stream>>>(w_qkv, wqkvb, nwqkv / 4);
  f2b_kernel<<<dim3((nwo / 4 + 255) / 256), 256, 0, stream>>>(w_o, wob, nwo / 4);
  rope_table_kernel<<<dim3((S_ * 64 + 255) / 256), 256, 0, stream>>>(cs, sn);

  // qkv: 256x256 tiles, grid 16*12 = 192 (%8==0)
  gemm8p_kernel<<<dim3(192), 512, 0, stream>>>(xb, wqkvb, qkv, B_ * S_, QKV_O, D_, QKV_O / 256);

  rope_qk_kernel<<<dim3((B_ * S_ * 20 * 64 + 255) / 256), 256, 0, stream>>>(qkv, cs, sn, Qb, K2b);
  v8_kernel<<<dim3(S_ / 8, B_ * NKV), 128, 0, stream>>>(qkv, V2b);

  attn32_kernel<<<dim3(512), 256, 0, stream>>>(Qb, K2b, V2b, attnb);

  // out-proj: 256x128 tiles, grid 16*16 = 256 (%8==0), 100% CU fill
  gemm8pn_kernel<<<dim3(256), 512, 0, stream>>>(attnb, wob, out, B_ * S_, D_, D_, D_ / 128);
}

// Round 12
// 205.892 us; speedup vs baseline: 1.4385x; 1.0223x over previous
//
#include <hip/hip_runtime.h>
#include <hip/hip_bf16.h>
#include <cstdint>
#include <cstddef>

typedef float f32x4 __attribute__((ext_vector_type(4)));
typedef float f32x16 __attribute__((ext_vector_type(16)));
typedef __bf16 bf16x8 __attribute__((ext_vector_type(8)));
typedef unsigned short us8v __attribute__((ext_vector_type(8)));
typedef unsigned short us4v __attribute__((ext_vector_type(4)));

constexpr int B_ = 2, S_ = 2048, D_ = 2048, NH = 16, NKV = 4, HD = 128;
constexpr int QKV_O = (NH + 2 * NKV) * HD;  // 3072

__device__ __forceinline__ unsigned short f2b(float f) {
  union { float f; uint32_t u; } v{f};
  uint32_t r = v.u + 0x7fffu + ((v.u >> 16) & 1u);  // RNE
  return (unsigned short)(r >> 16);
}

__device__ __forceinline__ uint32_t pk2(float a, float b) {
  union { __bf16 h[2]; uint32_t u; } v;
  v.h[0] = (__bf16)a; v.h[1] = (__bf16)b;
  return v.u;
}

__device__ __forceinline__ bf16x8 as_bf(us8v x) {
  union { us8v u; bf16x8 b; } v; v.u = x; return v.b;
}

__device__ __forceinline__ f32x4 mfma16(bf16x8 a, bf16x8 b, f32x4 c) {
  return __builtin_amdgcn_mfma_f32_16x16x32_bf16(a, b, c, 0, 0, 0);
}
__device__ __forceinline__ f32x16 mfma32(bf16x8 a, bf16x8 b, f32x16 c) {
  return __builtin_amdgcn_mfma_f32_32x32x16_bf16(a, b, c, 0, 0, 0);
}

// async global->LDS, 16B per lane; LDS dest = wave-uniform base + lane*16
__device__ __forceinline__ void gload_lds16(const unsigned short* g, unsigned short* l) {
  __builtin_amdgcn_global_load_lds(
      (const __attribute__((address_space(1))) unsigned int*)(uintptr_t)g,
      (__attribute__((address_space(3))) unsigned int*)(uintptr_t)l, 16, 0, 0);
}

// ---------------- f32 -> bf16 conversion (vectorized) ----------------
__global__ void f2b_kernel(const float* __restrict__ in, unsigned short* __restrict__ out, int n4) {
  int i = blockIdx.x * blockDim.x + threadIdx.x;
  if (i >= n4) return;
  float4 v = reinterpret_cast<const float4*>(in)[i];
  us4v o;
  o[0] = f2b(v.x); o[1] = f2b(v.y); o[2] = f2b(v.z); o[3] = f2b(v.w);
  reinterpret_cast<us4v*>(out)[i] = o;
}

// ---------------- RoPE cos/sin table: [S][64] ----------------
__global__ void rope_table_kernel(float* __restrict__ cs, float* __restrict__ sn) {
  int idx = blockIdx.x * blockDim.x + threadIdx.x;
  if (idx >= S_ * 64) return;
  int t = idx >> 6, i = idx & 63;
  float inv = __expf(-((float)(2 * i) / 128.0f) * 9.210340371976184f);
  float fr = (float)t * inv;
  cs[idx] = cosf(fr);
  sn[idx] = sinf(fr);
}

// ---------------- RoPE apply; Q -> [b,h,s,d] (pre-scaled by scale*log2e), K -> K2 ----------------
__global__ void rope_qk_kernel(const float* __restrict__ qkv, const float* __restrict__ cs,
                               const float* __restrict__ sn, unsigned short* __restrict__ Q,
                               unsigned short* __restrict__ K2) {
  int idx = blockIdx.x * blockDim.x + threadIdx.x;
  if (idx >= B_ * S_ * 20 * 64) return;
  int pr = idx & 63;
  int tmp = idx >> 6;
  int hh = tmp % 20; tmp /= 20;
  int s = tmp % S_;
  int b = tmp / S_;
  int off = (hh < 16) ? hh * HD : NH * HD + (hh - 16) * HD;
  float2 v = *reinterpret_cast<const float2*>(qkv + (size_t)(b * S_ + s) * QKV_O + off + 2 * pr);
  float c0 = cs[s * 64 + pr], s0 = sn[s * 64 + pr];
  // fold attn scale AND log2(e) into Q: softmax runs in exp2 domain
  float mult = (hh < 16) ? 0.12751744f : 1.0f;
  float o0 = (v.x * c0 - v.y * s0) * mult;
  float o1 = (v.x * s0 + v.y * c0) * mult;
  unsigned int packed = (unsigned)f2b(o0) | ((unsigned)f2b(o1) << 16);
  if (hh < 16) {
    *reinterpret_cast<unsigned*>(Q + (((size_t)(b * NH + hh) * S_ + s) * HD + 2 * pr)) = packed;
  } else {
    int bk = b * NKV + (hh - 16);
    size_t a = (((size_t)bk * 16 + (pr >> 2)) * S_ + s) * 8 + (pr & 3) * 2;
    *reinterpret_cast<unsigned*>(K2 + a) = packed;
  }
}

// ---------------- V pack: qkv f32 -> V2 bf16 [bk][s/8][d=128][8] ----------------
__global__ __launch_bounds__(128) void v8_kernel(const float* __restrict__ qkv,
                                                 unsigned short* __restrict__ V2) {
  int d = threadIdx.x;          // 0..127
  int g = blockIdx.x;           // s-group 0..255
  int bk = blockIdx.y;          // b*4+kvh
  const float* src = qkv + (size_t)((bk >> 2) * S_ + g * 8) * QKV_O + (NH + NKV) * HD +
                     (bk & 3) * HD + d;
  us8v o;
#pragma unroll
  for (int j = 0; j < 8; j++) o[j] = f2b(src[(size_t)j * QKV_O]);
  *reinterpret_cast<us8v*>(V2 + (((size_t)bk * 256 + g) * 128 + d) * 8) = o;
}

// ---------------- bf16 GEMM (256x256 8-phase, T1+T2+T3+T4+T5): C = A * B^T ----------------
__global__ __launch_bounds__(512, 2) void gemm8p_kernel(const unsigned short* __restrict__ A,
                                                        const unsigned short* __restrict__ Bm,
                                                        float* __restrict__ C, int M, int N,
                                                        int K, int nbx) {
  __shared__ unsigned short LDS[65536];  // A: [2][16384], B: +32768
  const int t = threadIdx.x;
  const int lane = t & 63, wid = t >> 6;
  const int wm = wid >> 2, wn = wid & 3;
  const int c = lane & 15, g4 = lane >> 4;
  const int cpx = gridDim.x >> 3;
  const int nid = (blockIdx.x & 7) * cpx + (blockIdx.x >> 3);
  const int m0 = (nid / nbx) * 256, n0 = (nid % nbx) * 256;

  const int sr = t >> 3, ss = t & 7;
  const int sg = ss ^ (sr & 7);
  const unsigned short* pa = A + (size_t)(m0 + sr) * K + sg * 8;
  const unsigned short* pb = Bm + (size_t)(n0 + sr) * K + sg * 8;
  unsigned short* ldw = (unsigned short*)&LDS[wid << 9];

  f32x4 acc[8][4] = {};
  bf16x8 bf[4][2];

#define STAGE_A(buf, j, kk0) \
  gload_lds16(pa + (size_t)(64 * (j)) * K + (kk0), ldw + (buf)*16384 + (j)*4096)
#define STAGE_B(buf, j, kk0) \
  gload_lds16(pb + (size_t)(64 * (j)) * K + (kk0), ldw + 32768 + (buf)*16384 + (j)*4096)

#define LDA(buf, m, kk) \
  as_bf(*reinterpret_cast<const us8v*>( \
      &LDS[(buf)*16384 + (wm * 128 + (m)*16 + c) * 64 + ((((kk) << 2) | g4) ^ (c & 7)) * 8]))
#define LDB(buf, n, kk) \
  as_bf(*reinterpret_cast<const us8v*>( \
      &LDS[32768 + (buf)*16384 + (wn * 64 + (n)*16 + c) * 64 + ((((kk) << 2) | g4) ^ (c & 7)) * 8]))

#pragma unroll
  for (int j = 0; j < 4; j++) STAGE_B(0, j, 0);
#pragma unroll
  for (int j = 0; j < 4; j++) STAGE_A(0, j, 0);
  asm volatile("s_waitcnt vmcnt(0)" ::: "memory");
  __builtin_amdgcn_s_barrier();

  const int NT = K >> 6;
  for (int tt = 0; tt < NT; ++tt) {
    const int cur = tt & 1, nxt = cur ^ 1;
    const int kn = (tt + 1) << 6;
    const bool st = (tt + 1) < NT;
    bf16x8 a00, a01, a10, a11;

#define MFMA_PAIR(mlo)                                    \
  __builtin_amdgcn_s_setprio(1);                          \
  _Pragma("unroll") for (int n = 0; n < 4; n++) {         \
    acc[(mlo)][n] = mfma16(a00, bf[n][0], acc[(mlo)][n]); \
    acc[(mlo) + 1][n] = mfma16(a10, bf[n][0], acc[(mlo) + 1][n]); \
    acc[(mlo)][n] = mfma16(a01, bf[n][1], acc[(mlo)][n]); \
    acc[(mlo) + 1][n] = mfma16(a11, bf[n][1], acc[(mlo) + 1][n]); \
  }                                                       \
  __builtin_amdgcn_s_setprio(0);

    // ---- P0 ----
#pragma unroll
    for (int n = 0; n < 4; n++) { bf[n][0] = LDB(cur, n, 0); bf[n][1] = LDB(cur, n, 1); }
    a00 = LDA(cur, 0, 0); a01 = LDA(cur, 0, 1); a10 = LDA(cur, 1, 0); a11 = LDA(cur, 1, 1);
    if (st) { STAGE_B(nxt, 0, kn); STAGE_B(nxt, 1, kn); }
    __builtin_amdgcn_s_barrier();
    MFMA_PAIR(0)
    __builtin_amdgcn_s_barrier();
    // ---- P1 ----
    a00 = LDA(cur, 2, 0); a01 = LDA(cur, 2, 1); a10 = LDA(cur, 3, 0); a11 = LDA(cur, 3, 1);
    if (st) { STAGE_B(nxt, 2, kn); STAGE_B(nxt, 3, kn); }
    asm volatile("s_waitcnt vmcnt(4)" ::: "memory");
    __builtin_amdgcn_s_barrier();
    MFMA_PAIR(2)
    __builtin_amdgcn_s_barrier();
    // ---- P2 ----
    a00 = LDA(cur, 4, 0); a01 = LDA(cur, 4, 1); a10 = LDA(cur, 5, 0); a11 = LDA(cur, 5, 1);
    if (st) { STAGE_A(nxt, 0, kn); STAGE_A(nxt, 2, kn); }
    __builtin_amdgcn_s_barrier();
    MFMA_PAIR(4)
    __builtin_amdgcn_s_barrier();
    // ---- P3 ----
    a00 = LDA(cur, 6, 0); a01 = LDA(cur, 6, 1); a10 = LDA(cur, 7, 0); a11 = LDA(cur, 7, 1);
    if (st) { STAGE_A(nxt, 1, kn); STAGE_A(nxt, 3, kn); }
    asm volatile("s_waitcnt vmcnt(2)" ::: "memory");
    __builtin_amdgcn_s_barrier();
    MFMA_PAIR(6)
    __builtin_amdgcn_s_barrier();
#undef MFMA_PAIR
  }

#pragma unroll
  for (int m = 0; m < 8; m++)
#pragma unroll
    for (int n = 0; n < 4; n++)
#pragma unroll
      for (int r = 0; r < 4; r++)
        C[(size_t)(m0 + wm * 128 + m * 16 + g4 * 4 + r) * N + n0 + wn * 64 + n * 16 + c] =
            acc[m][n][r];
#undef STAGE_A
#undef STAGE_B
#undef LDA
#undef LDB
}

// ---------------- bf16 GEMM (256x128 8-phase, f32 C): out-proj, 100% CU fill ----------------
__global__ __launch_bounds__(512, 2) void gemm8pn_kernel(const unsigned short* __restrict__ A,
                                                         const unsigned short* __restrict__ Bm,
                                                         float* __restrict__ C, int M, int N,
                                                         int K, int nbx) {
  __shared__ unsigned short LDS[49152];  // A: [2][16384]; B at 32768 + [2][8192]
  const int t = threadIdx.x;
  const int lane = t & 63, wid = t >> 6;
  const int wm = wid >> 2, wn = wid & 3;
  const int c = lane & 15, g4 = lane >> 4;
  const int cpx = gridDim.x >> 3;
  const int nid = (blockIdx.x & 7) * cpx + (blockIdx.x >> 3);
  const int m0 = (nid / nbx) * 256, n0 = (nid % nbx) * 128;

  const int sr = t >> 3, ss = t & 7;
  const int sg = ss ^ (sr & 7);
  const unsigned short* pa = A + (size_t)(m0 + sr) * K + sg * 8;
  const unsigned short* pb = Bm + (size_t)(n0 + sr) * K + sg * 8;
  unsigned short* ldw = (unsigned short*)&LDS[wid << 9];

  f32x4 acc[8][2] = {};
  bf16x8 bf[2][2];

#define STAGE_A(buf, j, kk0) \
  gload_lds16(pa + (size_t)(64 * (j)) * K + (kk0), ldw + (buf)*16384 + (j)*4096)
#define STAGE_B(buf, j, kk0) \
  gload_lds16(pb + (size_t)(64 * (j)) * K + (kk0), ldw + 32768 + (buf)*8192 + (j)*4096)

#define LDA(buf, m, kk) \
  as_bf(*reinterpret_cast<const us8v*>( \
      &LDS[(buf)*16384 + (wm * 128 + (m)*16 + c) * 64 + ((((kk) << 2) | g4) ^ (c & 7)) * 8]))
#define LDB(buf, n, kk) \
  as_bf(*reinterpret_cast<const us8v*>( \
      &LDS[32768 + (buf)*8192 + (wn * 32 + (n)*16 + c) * 64 + ((((kk) << 2) | g4) ^ (c & 7)) * 8]))

  STAGE_B(0, 0, 0); STAGE_B(0, 1, 0);
#pragma unroll
  for (int j = 0; j < 4; j++) STAGE_A(0, j, 0);
  asm volatile("s_waitcnt vmcnt(0)" ::: "memory");
  __builtin_amdgcn_s_barrier();

  const int NT = K >> 6;
  for (int tt = 0; tt < NT; ++tt) {
    const int cur = tt & 1, nxt = cur ^ 1;
    const int kn = (tt + 1) << 6;
    const bool st = (tt + 1) < NT;
    bf16x8 a00, a01, a10, a11;

#define MFMA_PAIR(mlo)                                    \
  __builtin_amdgcn_s_setprio(1);                          \
  _Pragma("unroll") for (int n = 0; n < 2; n++) {         \
    acc[(mlo)][n] = mfma16(a00, bf[n][0], acc[(mlo)][n]); \
    acc[(mlo) + 1][n] = mfma16(a10, bf[n][0], acc[(mlo) + 1][n]); \
    acc[(mlo)][n] = mfma16(a01, bf[n][1], acc[(mlo)][n]); \
    acc[(mlo) + 1][n] = mfma16(a11, bf[n][1], acc[(mlo) + 1][n]); \
  }                                                       \
  __builtin_amdgcn_s_setprio(0);

    // ---- P0 ----
#pragma unroll
    for (int n = 0; n < 2; n++) { bf[n][0] = LDB(cur, n, 0); bf[n][1] = LDB(cur, n, 1); }
    a00 = LDA(cur, 0, 0); a01 = LDA(cur, 0, 1); a10 = LDA(cur, 1, 0); a11 = LDA(cur, 1, 1);
    if (st) STAGE_B(nxt, 0, kn);
    __builtin_amdgcn_s_barrier();
    MFMA_PAIR(0)
    __builtin_amdgcn_s_barrier();
    // ---- P1 ----
    a00 = LDA(cur, 2, 0); a01 = LDA(cur, 2, 1); a10 = LDA(cur, 3, 0); a11 = LDA(cur, 3, 1);
    if (st) STAGE_B(nxt, 1, kn);
    asm volatile("s_waitcnt vmcnt(2)" ::: "memory");
    __builtin_amdgcn_s_barrier();
    MFMA_PAIR(2)
    __builtin_amdgcn_s_barrier();
    // ---- P2 ----
    a00 = LDA(cur, 4, 0); a01 = LDA(cur, 4, 1); a10 = LDA(cur, 5, 0); a11 = LDA(cur, 5, 1);
    if (st) { STAGE_A(nxt, 0, kn); STAGE_A(nxt, 2, kn); }
    __builtin_amdgcn_s_barrier();
    MFMA_PAIR(4)
    __builtin_amdgcn_s_barrier();
    // ---- P3 ----
    a00 = LDA(cur, 6, 0); a01 = LDA(cur, 6, 1); a10 = LDA(cur, 7, 0); a11 = LDA(cur, 7, 1);
    if (st) { STAGE_A(nxt, 1, kn); STAGE_A(nxt, 3, kn); }
    asm volatile("s_waitcnt vmcnt(2)" ::: "memory");
    __builtin_amdgcn_s_barrier();
    MFMA_PAIR(6)
    __builtin_amdgcn_s_barrier();
#undef MFMA_PAIR
  }

#pragma unroll
  for (int m = 0; m < 8; m++)
#pragma unroll
    for (int n = 0; n < 2; n++)
#pragma unroll
      for (int r = 0; r < 4; r++)
        C[(size_t)(m0 + wm * 128 + m * 16 + g4 * 4 + r) * N + n0 + wn * 32 + n * 16 + c] =
            acc[m][n][r];
#undef STAGE_A
#undef STAGE_B
#undef LDA
#undef LDB
}

// ---------------- Flash attention: SIMD-balanced pairing + XCD-grouped, exp2 softmax ----------------
// 8 waves/block (512 thr), 256 blocks = 1/CU. Wave w: pair a = bq*4+(w&3),
// tile = (w>>2) ? 63-a : a. SIMD s hosts waves s (cost a+1) and s+4 (cost 64-a):
// per-SIMD total = 65 steps, uniform everywhere. Zero LDS, no barriers.
__global__ __launch_bounds__(512, 2) void attn32_kernel(const unsigned short* __restrict__ Q,
                                                        const unsigned short* __restrict__ K2,
                                                        const unsigned short* __restrict__ V2,
                                                        unsigned short* __restrict__ O) {
  int t = threadIdx.x;
  int lane = t & 63, wid = t >> 6;
  int l31 = lane & 31, hi = lane >> 5;

  int id = blockIdx.x;
  int g = id & 7, s5 = id >> 3;          // g = (b,kvh) group -> XCD g; s5 = 0..31
  int b = g >> 2, kvh = g & 3;
  int h = kvh * 4 + (s5 & 3);
  int bk = b * NKV + kvh;
  int a = (s5 >> 2) * 4 + (wid & 3);     // pair index 0..31
  int tw = (wid >> 2) ? (63 - a) : a;    // cheap on SIMD w, heavy on same SIMD (w+4)
  int qw = tw * 32;

  const unsigned short* Qp = Q + ((size_t)(b * NH + h) * S_ + qw) * HD + (size_t)l31 * HD + hi * 8;
  const unsigned short* Kp = K2 + (((size_t)bk * 16 + hi) * S_ + l31) * 8;
  const unsigned short* Vp = V2 + (((size_t)bk * 256 + hi) * 128 + l31) * 8;

  bf16x8 qf[8];
#pragma unroll
  for (int kk = 0; kk < 8; kk++)
    qf[kk] = as_bf(*reinterpret_cast<const us8v*>(Qp + kk * 16));

  f32x16 oacc[4] = {};
  float mrow = -1e30f, lsum = 0.0f;

  bf16x8 kA[8], kB[8];

  auto loadK = [&](bf16x8(&kf)[8], int kv) {
    const unsigned short* kp = Kp + (size_t)kv * 8;
#pragma unroll
    for (int kk = 0; kk < 8; kk++)
      kf[kk] = as_bf(*reinterpret_cast<const us8v*>(kp + (size_t)kk * 2 * S_ * 8));
  };

  auto step = [&](bf16x8(&kf)[8], bf16x8(&kn)[8], int kv0) {
    bf16x8 vf[8];
    const unsigned short* vp = Vp + (size_t)kv0 * 128;
#pragma unroll
    for (int dt = 0; dt < 4; dt++) {
      vf[2 * dt] = as_bf(*reinterpret_cast<const us8v*>(vp + dt * 256));
      vf[2 * dt + 1] = as_bf(*reinterpret_cast<const us8v*>(vp + 2048 + dt * 256));
    }
    if (kv0 + 32 <= qw) loadK(kn, kv0 + 32);

    f32x16 sa = {}, sb = {};
    __builtin_amdgcn_s_setprio(1);
#pragma unroll
    for (int kk = 0; kk < 4; kk++) {
      sa = mfma32(kf[2 * kk], qf[2 * kk], sa);
      sb = mfma32(kf[2 * kk + 1], qf[2 * kk + 1], sb);
    }
    __builtin_amdgcn_s_setprio(0);
    f32x16 s = sa + sb;

    if (kv0 == qw) {  // diagonal tile: causal mask
      int qg = qw + l31;
#pragma unroll
      for (int r = 0; r < 16; r++) {
        int kvg = kv0 + (r & 3) + 8 * (r >> 2) + 4 * hi;
        if (kvg > qg) s[r] = -1e30f;
      }
    }

    float pm = fmaxf(s[0], s[1]);
#pragma unroll
    for (int r = 2; r < 16; r++) pm = fmaxf(pm, s[r]);
    pm = fmaxf(pm, __shfl_xor(pm, 32));

    bool nore = __all(pm <= mrow + 11.54f) != 0;  // defer-max, log2 units
    float mn = nore ? mrow : fmaxf(mrow, pm);
    float part = 0.0f;
    uint32_t w[8];
#pragma unroll
    for (int jj = 0; jj < 8; jj++) {
      float e0 = __builtin_amdgcn_exp2f(s[2 * jj] - mn);
      float e1 = __builtin_amdgcn_exp2f(s[2 * jj + 1] - mn);
      part += e0 + e1;
      w[jj] = pk2(e0, e1);
    }
    part += __shfl_xor(part, 32);
    if (nore) {
      lsum += part;
    } else {
      float alpha = __builtin_amdgcn_exp2f(mrow - mn);  // per q-row l31
      lsum = lsum * alpha + part;
      mrow = mn;
#pragma unroll
      for (int r = 0; r < 16; r++) {
        float af = __shfl(alpha, (r & 3) + 8 * (r >> 2) + 4 * hi);
#pragma unroll
        for (int dt = 0; dt < 4; dt++) oacc[dt][r] *= af;
      }
    }

    // ---- P -> A-fragments via lane^32 exchange ----
    uint32_t sw[8];
#pragma unroll
    for (int jj = 0; jj < 8; jj++) sw[jj] = __shfl_xor(w[jj], 32);
    union { uint32_t u[4]; bf16x8 v; } pa0, pa1;
    if (hi == 0) {
      pa0.u[0] = w[0]; pa0.u[1] = w[1]; pa0.u[2] = sw[0]; pa0.u[3] = sw[1];
      pa1.u[0] = w[4]; pa1.u[1] = w[5]; pa1.u[2] = sw[4]; pa1.u[3] = sw[5];
    } else {
      pa0.u[0] = sw[2]; pa0.u[1] = sw[3]; pa0.u[2] = w[2]; pa0.u[3] = w[3];
      pa1.u[0] = sw[6]; pa1.u[1] = sw[7]; pa1.u[2] = w[6]; pa1.u[3] = w[7];
    }

    __builtin_amdgcn_s_setprio(1);
#pragma unroll
    for (int dt = 0; dt < 4; dt++) {
      oacc[dt] = mfma32(pa0.v, vf[2 * dt], oacc[dt]);
      oacc[dt] = mfma32(pa1.v, vf[2 * dt + 1], oacc[dt]);
    }
    __builtin_amdgcn_s_setprio(0);
  };

  loadK(kA, 0);
  int kv0 = 0;
  while (true) {
    step(kA, kB, kv0);
    kv0 += 32;
    if (kv0 > qw) break;
    step(kB, kA, kv0);
    kv0 += 32;
    if (kv0 > qw) break;
  }

  // ---- epilogue: O[q=crow(r,hi)][d=dt*32+l31] ----
  float il = 1.0f / lsum;
  unsigned short* Op = O + ((size_t)b * S_ + qw) * D_ + h * HD;
#pragma unroll
  for (int r = 0; r < 16; r++) {
    int row = (r & 3) + 8 * (r >> 2) + 4 * hi;
    float sc = __shfl(il, row);
#pragma unroll
    for (int dt = 0; dt < 4; dt++)
      Op[(size_t)row * D_ + dt * 32 + l31] = f2b(oacc[dt][r] * sc);
  }
}

extern "C" void kernel_launch(void* const* d_in, const int* in_sizes, int n_in, void* d_out,
                              int out_size, void* d_ws, size_t ws_size, hipStream_t stream) {
  const float* x = (const float*)d_in[0];
  const float* w_qkv = (const float*)d_in[1];
  const float* w_o = (const float*)d_in[2];
  float* out = (float*)d_out;

  char* ws = (char*)d_ws;
  size_t off = 0;
  auto alloc = [&](size_t bytes) -> void* {
    void* p = ws + off;
    off += (bytes + 255) & ~(size_t)255;
    return p;
  };
  const size_t nx = (size_t)B_ * S_ * D_;
  const size_t nwqkv = (size_t)QKV_O * D_;
  const size_t nwo = (size_t)D_ * D_;
  unsigned short* xb = (unsigned short*)alloc(nx * 2);
  unsigned short* wqkvb = (unsigned short*)alloc(nwqkv * 2);
  unsigned short* wob = (unsigned short*)alloc(nwo * 2);
  float* qkv = (float*)alloc((size_t)B_ * S_ * QKV_O * 4);
  unsigned short* Qb = (unsigned short*)alloc((size_t)B_ * NH * S_ * HD * 2);
  unsigned short* K2b = (unsigned short*)alloc((size_t)B_ * NKV * S_ * HD * 2);
  unsigned short* V2b = (unsigned short*)alloc((size_t)B_ * NKV * HD * S_ * 2);
  unsigned short* attnb = (unsigned short*)alloc((size_t)B_ * S_ * D_ * 2);
  float* cs = (float*)alloc((size_t)S_ * 64 * 4);
  float* sn = (float*)alloc((size_t)S_ * 64 * 4);

  f2b_kernel<<<dim3((nx / 4 + 255) / 256), 256, 0, stream>>>(x, xb, nx / 4);
  f2b_kernel<<<dim3((nwqkv / 4 + 255) / 256), 256, 0, stream>>>(w_qkv, wqkvb, nwqkv / 4);
  f2b_kernel<<<dim3((nwo / 4 + 255) / 256), 256, 0, stream>>>(w_o, wob, nwo / 4);
  rope_table_kernel<<<dim3((S_ * 64 + 255) / 256), 256, 0, stream>>>(cs, sn);

  // qkv: 256x256 tiles, grid 16*12 = 192 (%8==0)
  gemm8p_kernel<<<dim3(192), 512, 0, stream>>>(xb, wqkvb, qkv, B_ * S_, QKV_O, D_, QKV_O / 256);

  rope_qk_kernel<<<dim3((B_ * S_ * 20 * 64 + 255) / 256), 256, 0, stream>>>(qkv, cs, sn, Qb, K2b);
  v8_kernel<<<dim3(S_ / 8, B_ * NKV), 128, 0, stream>>>(qkv, V2b);

  attn32_kernel<<<dim3(256), 512, 0, stream>>>(Qb, K2b, V2b, attnb);

  // out-proj: 256x128 tiles, grid 16*16 = 256 (%8==0), 100% CU fill
  gemm8pn_kernel<<<dim3(256), 512, 0, stream>>>(attnb, wob, out, B_ * S_, D_, D_, D_ / 128);
}